// Round 2
// baseline (1903.064 us; speedup 1.0000x reference)
//
#include <hip/hip_runtime.h>

typedef unsigned int uint;
typedef unsigned short ushort;

typedef __attribute__((ext_vector_type(8))) __bf16 bf16x8;
typedef __attribute__((ext_vector_type(4))) float f32x4;

#define B_ 64
#define S_ 256
#define D_ 512
#define H_ 8
#define DFF_ 2048
#define V_ 128
#define L_ 6
#define BS_ (B_ * S_)

__device__ __forceinline__ float blo(uint u) { return __uint_as_float(u << 16); }
__device__ __forceinline__ float bhi(uint u) { return __uint_as_float(u & 0xffff0000u); }
__device__ __forceinline__ float b2f(ushort u) { return __uint_as_float(((uint)u) << 16); }
__device__ __forceinline__ ushort f2b(float f) {
  uint u = __float_as_uint(f);
  return (ushort)((u + 0x7fffu + ((u >> 16) & 1u)) >> 16);  // RTNE
}
__device__ __forceinline__ uint pack2(float a, float b) {
  return (uint)f2b(a) | ((uint)f2b(b) << 16);
}

#define GLOAD16(gp, lp)                                                        \
  __builtin_amdgcn_global_load_lds(                                            \
      (const __attribute__((address_space(1))) void*)(gp),                     \
      (__attribute__((address_space(3))) void*)(lp), 16, 0, 0)

// compiler-fenced raw barrier (no vmcnt(0) drain!) + counted vmcnt waits
#define BARX()                                                                 \
  do {                                                                         \
    asm volatile("" ::: "memory");                                             \
    __builtin_amdgcn_s_barrier();                                              \
    asm volatile("" ::: "memory");                                             \
  } while (0)
#define WAITV(N) asm volatile("s_waitcnt vmcnt(" #N ")" ::: "memory")
// rule #18: after asm ds_read, fence MFMA with lgkmcnt(0) + sched_barrier(0)
#define WAITL()                                                                \
  do {                                                                         \
    asm volatile("s_waitcnt lgkmcnt(0)" ::: "memory");                         \
    __builtin_amdgcn_sched_barrier(0);                                         \
  } while (0)

// inline-asm LDS read: invisible to SIInsertWaitcnts' LDS-DMA alias tracking,
// so the compiler cannot insert vmcnt drains before it (the round-1 collapse).
// Generic LDS pointer low 32 bits == LDS byte offset (4GiB-aligned aperture).
__device__ __forceinline__ bf16x8 ldsrd128(const ushort* p) {
  bf16x8 r;
  asm volatile("ds_read_b128 %0, %1" : "=v"(r) : "v"((uint)(uintptr_t)p));
  return r;
}

// -------- fp32 -> bf16 bulk conversion (one-time per launch) ---------------
__global__ __launch_bounds__(256) void conv_kernel(const float* __restrict__ src,
                                                   ushort* __restrict__ dst) {
  size_t p = (size_t)blockIdx.x * 256 + threadIdx.x;
  float2 v = ((const float2*)src)[p];
  ((uint*)dst)[p] = pack2(v.x, v.y);
}

// -------- embedding: x16 = bf16(emb[tgt] + pos); emb/pos fp32 ---------------
__global__ __launch_bounds__(256) void embed_kernel(
    const int* __restrict__ tgt, const float* __restrict__ emb,
    const float* __restrict__ pos, ushort* __restrict__ x16) {
  int p = blockIdx.x * 256 + threadIdx.x;
  int row = p >> 8;
  int d2 = p & 255;
  int s = row & (S_ - 1);
  int tok = tgt[row];
  float2 e = ((const float2*)emb)[tok * 256 + d2];
  float2 pp = ((const float2*)pos)[s * 256 + d2];
  ((uint*)x16)[p] = pack2(e.x + pp.x, e.y + pp.y);
}

// ===========================================================================
// 256x256-tile deep-pipeline GEMM. v2 changes vs round 1:
//  (a) fragment loads are inline-asm ds_read_b128 + manual lgkmcnt(0) +
//      sched_barrier(0): stops SIInsertWaitcnts from draining the prefetch
//      queue (vmcnt) before every phase's LDS reads (round-1 stall).
//  (b) 2-bit XOR swizzle col ^= ((r>>1)&1)<<3 | ((r>>2)&1)<<4 -> fragment
//      reads hit 8 distinct 4-bank slots (2-way = free, m136).
// C = A[.,K](As) . W[N][K](Ws)^T + bias.
// MODE 0: bf16(acc+bias)  1: relu  2: bf16 C+=acc  4: Q-prescale (cols<512)
// Requires: M%256==0, N%256==0, K%32==0, K>=96. 512 thr, dyn LDS 139264 B.
// ===========================================================================
template <int MODE>
__global__ __launch_bounds__(512) void gemm256(
    const ushort* __restrict__ A, const ushort* __restrict__ W,
    const float* __restrict__ bias, ushort* __restrict__ C, int N, int K,
    int As, int Ws, int Cs) {
  extern __shared__ ushort shl[];
  const int tid = threadIdx.x;
  const int wv = tid >> 6, lane = tid & 63;
  const int tr = lane & 15, tq = lane >> 4;
  const int wm = wv >> 2, wn = wv & 3;  // 2 (M) x 4 (N) wave grid
  const int m0 = blockIdx.y << 8, n0 = blockIdx.x << 8;

  // staging: thread covers lds row rr = tid>>2, 16B chunk (tid&3); source
  // global col pre-swizzled so linear LDS holds tile[r][c ^ swz(r)]
  const int rr = tid >> 2;
  const int sw = (((rr >> 1) & 1) << 3) | (((rr >> 2) & 1) << 4);
  const int cswz = ((tid & 3) * 8) ^ sw;
  const ushort* gA0 = A + (size_t)(m0 + rr) * As + cswz;
  const ushort* gA1 = A + (size_t)(m0 + 128 + rr) * As + cswz;
  const ushort* gB0 = W + (size_t)(n0 + rr) * Ws + cswz;
  const ushort* gB1 = W + (size_t)(n0 + 128 + rr) * Ws + cswz;

  // fragment ds_read offsets (row % 16 == tr for all frags)
  const int swr = (((tr >> 1) & 1) << 3) | (((tr >> 2) & 1) << 4);
  const int cu = (tq * 8) ^ swr;
  const int aoff = (wm * 128 + tr) * 32 + cu;
  const int boff = (wn * 64 + tr) * 32 + cu;

  f32x4 acc[8][4];
#pragma unroll
  for (int i = 0; i < 8; ++i)
#pragma unroll
    for (int j = 0; j < 4; ++j) acc[i][j] = (f32x4)(0.f);

  const int NT = K >> 5;  // BK = 32

  // slot stride 16384 ushorts (32KB): [A 8192][B 8192]; half stride 4096.
#define STG_A(t)                                                               \
  do {                                                                         \
    ushort* d_ = shl + (((t) & 3) << 14) + wv * 512;                           \
    GLOAD16(gA0 + (t) * 32, d_);                                               \
    GLOAD16(gA1 + (t) * 32, d_ + 4096);                                        \
  } while (0)
#define STG_B(t)                                                               \
  do {                                                                         \
    ushort* d_ = shl + (((t) & 3) << 14) + 8192 + wv * 512;                    \
    GLOAD16(gB0 + (t) * 32, d_);                                               \
    GLOAD16(gB1 + (t) * 32, d_ + 4096);                                        \
  } while (0)

  // prologue: stage tiles 0,1,2 (12 loads/wave); WAITV(8) -> own tile-0 loads
  // landed; BARX -> ALL waves' tile-0 loads landed.
  STG_A(0); STG_B(0);
  STG_A(1); STG_B(1);
  STG_A(2); STG_B(2);
  WAITV(8);
  BARX();

  for (int t = 0; t < NT; ++t) {
    const ushort* sA = shl + ((t & 3) << 14);
    const ushort* sB = sA + 8192;
    bf16x8 bv[4], av[4];
    // ---- phase A: read B[0..3] + A[0..3] (8 asm ds_read_b128); stage A(t+3)
#pragma unroll
    for (int j = 0; j < 4; ++j) bv[j] = ldsrd128(&sB[boff + j * 512]);
#pragma unroll
    for (int i = 0; i < 4; ++i) av[i] = ldsrd128(&sA[aoff + i * 512]);
    if (t + 3 < NT) STG_A(t + 3);
    BARX();
    WAITL();
    __builtin_amdgcn_s_setprio(1);
#pragma unroll
    for (int i = 0; i < 4; ++i)
#pragma unroll
      for (int j = 0; j < 4; ++j)
        acc[i][j] = __builtin_amdgcn_mfma_f32_16x16x32_bf16(bv[j], av[i],
                                                            acc[i][j], 0, 0, 0);
    __builtin_amdgcn_s_setprio(0);
    BARX();
    // ---- phase B: read A[4..7] (4 asm ds_read_b128); stage B(t+3)
#pragma unroll
    for (int i = 0; i < 4; ++i) av[i] = ldsrd128(&sA[aoff + (i + 4) * 512]);
    if (t + 3 < NT) STG_B(t + 3);
    BARX();
    WAITL();
    __builtin_amdgcn_s_setprio(1);
#pragma unroll
    for (int i = 0; i < 4; ++i)
#pragma unroll
      for (int j = 0; j < 4; ++j)
        acc[i + 4][j] = __builtin_amdgcn_mfma_f32_16x16x32_bf16(
            bv[j], av[i], acc[i + 4][j], 0, 0, 0);
    __builtin_amdgcn_s_setprio(0);
    // K-tile boundary: own tile t+1 landed; BARX makes it all-waves true.
    if (t + 3 < NT) {
      WAITV(8);
    } else if (t + 2 < NT) {
      WAITV(4);
    } else {
      WAITV(0);
    }
    BARX();
  }
#undef STG_A
#undef STG_B

  // ---- epilogue: acc (lane = 4 consecutive n at fixed m) -> LDS -> global
#pragma unroll
  for (int i = 0; i < 8; ++i)
#pragma unroll
    for (int j = 0; j < 4; ++j) {
      const int gn4 = n0 + wn * 64 + j * 16 + tq * 4;
      float b0 = 0.f, b1 = 0.f, b2 = 0.f, b3 = 0.f;
      if (MODE != 2) {
        float4 bb = ((const float4*)bias)[gn4 >> 2];
        b0 = bb.x; b1 = bb.y; b2 = bb.z; b3 = bb.w;
      }
      float v0 = acc[i][j][0] + b0, v1 = acc[i][j][1] + b1,
            v2 = acc[i][j][2] + b2, v3 = acc[i][j][3] + b3;
      if (MODE == 1) {
        v0 = fmaxf(v0, 0.f); v1 = fmaxf(v1, 0.f);
        v2 = fmaxf(v2, 0.f); v3 = fmaxf(v3, 0.f);
      }
      if (MODE == 4) {
        const float scl = (gn4 < 512) ? 0.18033688011112042f : 1.f;
        v0 *= scl; v1 *= scl; v2 *= scl; v3 *= scl;
      }
      uint2 pk;
      pk.x = pack2(v0, v1);
      pk.y = pack2(v2, v3);
      *(uint2*)&shl[(wm * 128 + i * 16 + tr) * 272 + wn * 64 + j * 16 +
                    tq * 4] = pk;
    }
  BARX();
#pragma unroll
  for (int u = 0; u < 16; ++u) {
    const int f = u * 512 + tid;
    const int row = f >> 5, sl = f & 31;
    uint4 val = *(const uint4*)&shl[row * 272 + sl * 8];
    ushort* gp = C + (size_t)(m0 + row) * Cs + n0 + sl * 8;
    if (MODE == 2) {
      uint4 c = *(const uint4*)gp;
      val.x = pack2(blo(val.x) + blo(c.x), bhi(val.x) + bhi(c.x));
      val.y = pack2(blo(val.y) + blo(c.y), bhi(val.y) + bhi(c.y));
      val.z = pack2(blo(val.z) + blo(c.z), bhi(val.z) + bhi(c.z));
      val.w = pack2(blo(val.w) + blo(c.w), bhi(val.w) + bhi(c.w));
    }
    *(uint4*)gp = val;
  }
}

// --- MFMA GEMM (m97 structure), kept for final fc (N=128 < 256) ------------
// MODE 3: fp32 acc+bias
template <int MODE>
__global__ __launch_bounds__(256) void gemm_bt(
    const ushort* __restrict__ A, const ushort* __restrict__ W,
    const float* __restrict__ bias, void* __restrict__ Cv, int N, int K,
    int As, int Ws, int Cs) {
  __shared__ ushort la[128 * 32];
  __shared__ ushort lb[128 * 32];
  const int tid = threadIdx.x;
  const int wv = tid >> 6, lane = tid & 63;
  const int m0 = blockIdx.y << 7, n0 = blockIdx.x << 7;
  const int wm = (wv >> 1) << 6, wn = (wv & 1) << 6;
  const int tr = lane & 15, tq = lane >> 4;

  const int lin0 = wv * 1024 + lane * 8;
  const int lin1 = lin0 + 512;
  const int am0 = lin0 >> 5, ac0 = lin0 & 31;
  const int am1 = lin1 >> 5, ac1 = lin1 & 31;

  const ushort* pa0 = A + (size_t)(m0 + am0) * As + ac0;
  const ushort* pa1 = A + (size_t)(m0 + am1) * As + ac1;
  const ushort* pb0 = W + (size_t)(n0 + am0) * Ws + ac0;
  const ushort* pb1 = W + (size_t)(n0 + am1) * Ws + ac1;
  ushort* la0 = &la[wv * 1024];
  ushort* la1 = &la[wv * 1024 + 512];
  ushort* lb0 = &lb[wv * 1024];
  ushort* lb1 = &lb[wv * 1024 + 512];

  f32x4 acc[4][4];
#pragma unroll
  for (int i = 0; i < 4; ++i)
#pragma unroll
    for (int j = 0; j < 4; ++j) acc[i][j] = (f32x4)(0.f);

  const int KT = K >> 5;
  for (int kt = 0; kt < KT; ++kt) {
    const int kb = kt << 5;
    GLOAD16(pa0 + kb, la0);
    GLOAD16(pa1 + kb, la1);
    GLOAD16(pb0 + kb, lb0);
    GLOAD16(pb1 + kb, lb1);
    __syncthreads();
    bf16x8 av[4], bv[4];
#pragma unroll
    for (int i = 0; i < 4; ++i)
      av[i] = *(const bf16x8*)&la[(wm + i * 16 + tr) * 32 + tq * 8];
#pragma unroll
    for (int j = 0; j < 4; ++j)
      bv[j] = *(const bf16x8*)&lb[(wn + j * 16 + tr) * 32 + tq * 8];
#pragma unroll
    for (int i = 0; i < 4; ++i)
#pragma unroll
      for (int j = 0; j < 4; ++j)
        acc[i][j] =
            __builtin_amdgcn_mfma_f32_16x16x32_bf16(av[i], bv[j], acc[i][j], 0, 0, 0);
    __syncthreads();
  }

#pragma unroll
  for (int j = 0; j < 4; ++j) {
    const int gn = n0 + wn + j * 16 + tr;
    float bj = 0.f;
    if (MODE != 2) bj = bias[gn];
    float scl = 1.f;
    if (MODE == 4) scl = (gn < 512) ? 0.18033688011112042f : 1.f;
#pragma unroll
    for (int i = 0; i < 4; ++i) {
      const int gmb = m0 + wm + i * 16 + tq * 4;
#pragma unroll
      for (int r = 0; r < 4; ++r) {
        const size_t idx = (size_t)(gmb + r) * Cs + gn;
        float v = acc[i][j][r] + bj;
        if (MODE == 1) v = fmaxf(v, 0.f);
        if (MODE == 4) v *= scl;
        if (MODE == 3)
          ((float*)Cv)[idx] = v;
        else if (MODE == 2) {
          ushort* C = (ushort*)Cv;
          C[idx] = f2b(b2f(C[idx]) + acc[i][j][r]);
        } else
          ((ushort*)Cv)[idx] = f2b(v);
      }
    }
  }
}

// --- batched MFMA GEMM, W fp32 converted during staging (Round-4-verified) --
// C_z = A_z[.,K](As) . W_z(Ws)[N][K]^T + bias_z ; z = blockIdx.z
__global__ __launch_bounds__(256) void gemm_btf(
    const ushort* __restrict__ A0, long zA, const float* __restrict__ W0,
    long zW, const float* __restrict__ bias0, long zb, ushort* __restrict__ C0,
    long zC, int N, int K, int As, int Ws, int Cs) {
  const int zz = blockIdx.z;
  const ushort* A = A0 + zA * zz;
  const float* W = W0 + zW * zz;
  const float* bias = bias0 + zb * zz;
  ushort* C = C0 + zC * zz;

  __shared__ ushort la[128 * 32];
  __shared__ ushort lb[128 * 32];
  const int tid = threadIdx.x;
  const int wv = tid >> 6, lane = tid & 63;
  const int m0 = blockIdx.y << 7, n0 = blockIdx.x << 7;
  const int wm = (wv >> 1) << 6, wn = (wv & 1) << 6;
  const int tr = lane & 15, tq = lane >> 4;

  const int lin0 = wv * 1024 + lane * 8;
  const int lin1 = lin0 + 512;
  const int am0 = lin0 >> 5, ac0 = lin0 & 31;
  const int am1 = lin1 >> 5, ac1 = lin1 & 31;

  const ushort* pa0 = A + (size_t)(m0 + am0) * As + ac0;
  const ushort* pa1 = A + (size_t)(m0 + am1) * As + ac1;
  const float* pb0 = W + (size_t)(n0 + am0) * Ws + ac0;
  const float* pb1 = W + (size_t)(n0 + am1) * Ws + ac1;

  f32x4 acc[4][4];
#pragma unroll
  for (int i = 0; i < 4; ++i)
#pragma unroll
    for (int j = 0; j < 4; ++j) acc[i][j] = (f32x4)(0.f);

  const int KT = K >> 5;
  for (int kt = 0; kt < KT; ++kt) {
    const int kb = kt << 5;
    uint4 ra0 = *(const uint4*)(pa0 + kb);
    uint4 ra1 = *(const uint4*)(pa1 + kb);
    float4 f00 = *(const float4*)(pb0 + kb);
    float4 f01 = *(const float4*)(pb0 + kb + 4);
    float4 f10 = *(const float4*)(pb1 + kb);
    float4 f11 = *(const float4*)(pb1 + kb + 4);
    uint4 rb0 = make_uint4(pack2(f00.x, f00.y), pack2(f00.z, f00.w),
                           pack2(f01.x, f01.y), pack2(f01.z, f01.w));
    uint4 rb1 = make_uint4(pack2(f10.x, f10.y), pack2(f10.z, f10.w),
                           pack2(f11.x, f11.y), pack2(f11.z, f11.w));
    __syncthreads();
    *(uint4*)&la[lin0] = ra0;
    *(uint4*)&la[lin1] = ra1;
    *(uint4*)&lb[lin0] = rb0;
    *(uint4*)&lb[lin1] = rb1;
    __syncthreads();
    bf16x8 av[4], bv[4];
#pragma unroll
    for (int i = 0; i < 4; ++i)
      av[i] = *(const bf16x8*)&la[(wm + i * 16 + tr) * 32 + tq * 8];
#pragma unroll
    for (int j = 0; j < 4; ++j)
      bv[j] = *(const bf16x8*)&lb[(wn + j * 16 + tr) * 32 + tq * 8];
#pragma unroll
    for (int i = 0; i < 4; ++i)
#pragma unroll
      for (int j = 0; j < 4; ++j)
        acc[i][j] =
            __builtin_amdgcn_mfma_f32_16x16x32_bf16(av[i], bv[j], acc[i][j], 0, 0, 0);
  }

#pragma unroll
  for (int j = 0; j < 4; ++j) {
    const int gn = n0 + wn + j * 16 + tr;
    const float bj = bias[gn];
#pragma unroll
    for (int i = 0; i < 4; ++i) {
      const int gmb = m0 + wm + i * 16 + tq * 4;
#pragma unroll
      for (int r = 0; r < 4; ++r)
        C[(size_t)(gmb + r) * Cs + gn] = f2b(acc[i][j][r] + bj);
    }
  }
}

// ---------------- MFMA causal attention v3 ----------------
// grid (2, H, B), 128 threads (2 waves). Wave g owns q-chunk qc=2*qp+g.
// K staged [key][d]; V staged TRANSPOSED [d][key] so PV B-frags are b128.
// Q pre-scaled by log2(e)/8 in QKV GEMM. In-place output over q-slice.
// P relay is per-wave LDS (in-order LDS pipe) -> no barrier between P and PV.
__global__ __launch_bounds__(128) void attn_mfma(ushort* __restrict__ qkv) {
  __shared__ ushort lk[64 * 72];      // K chunk  [key][64+8]
  __shared__ ushort lvT[64 * 72];     // V^T      [d][64+8]
  __shared__ ushort lp[2 * 64 * 72];  // per-wave P [qrow][64+8]
  const int qp = blockIdx.x, h = blockIdx.y, b = blockIdx.z;
  const int tid = threadIdx.x;
  const int g = tid >> 6, lane = tid & 63;
  const int tr = lane & 15, tq = lane >> 4;
  const int qc = qp * 2 + g;
  const int q0 = qc << 6;
  ushort* myp = &lp[g * 64 * 72];

  bf16x8 qf[4][2];
#pragma unroll
  for (int i = 0; i < 4; ++i)
#pragma unroll
    for (int s = 0; s < 2; ++s)
      qf[i][s] = *(const bf16x8*)(qkv +
                                  (size_t)(b * 256 + q0 + i * 16 + tr) * 1536 +
                                  h * 64 + s * 32 + tq * 8);

  f32x4 o[4][4];
  float pl[4][4];
#pragma unroll
  for (int i = 0; i < 4; ++i)
#pragma unroll
    for (int j = 0; j < 4; ++j) {
      o[i][j] = (f32x4)(0.f);
      pl[i][j] = 0.f;
    }

  const int key = tid >> 1, half = tid & 1;
  const int cmax = qp * 2 + 1;
  for (int c = 0; c <= cmax; ++c) {
    __syncthreads();  // protect prior chunk's lk/lvT reads
    const ushort* gk =
        qkv + (size_t)(b * 256 + c * 64 + key) * 1536 + 512 + h * 64 + half * 32;
#pragma unroll
    for (int u = 0; u < 4; ++u)
      *(uint4*)&lk[key * 72 + half * 32 + u * 8] = *(const uint4*)(gk + u * 8);
    ushort vloc[32];
#pragma unroll
    for (int u = 0; u < 4; ++u)
      *(uint4*)&vloc[u * 8] = *(const uint4*)(gk + 512 + u * 8);
#pragma unroll
    for (int dd = 0; dd < 32; ++dd)
      lvT[(half * 32 + dd) * 72 + key] = vloc[dd];
    __syncthreads();

    if (c <= qc) {
      // S = Q . K^T
      f32x4 Sv[4][4];
#pragma unroll
      for (int i = 0; i < 4; ++i)
#pragma unroll
        for (int j = 0; j < 4; ++j) Sv[i][j] = (f32x4)(0.f);
      bf16x8 kf[4][2];
#pragma unroll
      for (int j = 0; j < 4; ++j)
#pragma unroll
        for (int s = 0; s < 2; ++s)
          kf[j][s] = *(const bf16x8*)&lk[(j * 16 + tr) * 72 + s * 32 + tq * 8];
#pragma unroll
      for (int i = 0; i < 4; ++i)
#pragma unroll
        for (int j = 0; j < 4; ++j) {
          Sv[i][j] = __builtin_amdgcn_mfma_f32_16x16x32_bf16(qf[i][0], kf[j][0],
                                                             Sv[i][j], 0, 0, 0);
          Sv[i][j] = __builtin_amdgcn_mfma_f32_16x16x32_bf16(qf[i][1], kf[j][1],
                                                             Sv[i][j], 0, 0, 0);
        }
      // exp2 (Q pre-scaled) + causal mask + partial rowsums + P -> own LDS
      const bool diag = (c == qc);
#pragma unroll
      for (int i = 0; i < 4; ++i)
#pragma unroll
        for (int j = 0; j < 4; ++j)
#pragma unroll
          for (int r = 0; r < 4; ++r) {
            float e = exp2f(Sv[i][j][r]);
            if (diag && (j * 16 + tr) > (i * 16 + tq * 4 + r)) e = 0.f;
            pl[i][r] += e;
            myp[(i * 16 + tq * 4 + r) * 72 + j * 16 + tr] =
                (ushort)(__float_as_uint(e) >> 16);  // trunc: P in [0,1]
          }
      // O += P . V  (same-wave LDS RAW: in-order DS pipe, no barrier)
#pragma unroll
      for (int s = 0; s < 2; ++s) {
        bf16x8 vf[4], af[4];
#pragma unroll
        for (int jn = 0; jn < 4; ++jn)
          vf[jn] = *(const bf16x8*)&lvT[(jn * 16 + tr) * 72 + s * 32 + tq * 8];
#pragma unroll
        for (int im = 0; im < 4; ++im)
          af[im] = *(const bf16x8*)&myp[(im * 16 + tr) * 72 + s * 32 + tq * 8];
#pragma unroll
        for (int im = 0; im < 4; ++im)
#pragma unroll
          for (int jn = 0; jn < 4; ++jn)
            o[im][jn] = __builtin_amdgcn_mfma_f32_16x16x32_bf16(af[im], vf[jn],
                                                                o[im][jn], 0, 0, 0);
      }
    }
  }

#pragma unroll
  for (int i = 0; i < 4; ++i)
#pragma unroll
    for (int r = 0; r < 4; ++r) {
      float v = pl[i][r];
      v += __shfl_xor(v, 1, 64);
      v += __shfl_xor(v, 2, 64);
      v += __shfl_xor(v, 4, 64);
      v += __shfl_xor(v, 8, 64);
      pl[i][r] = 1.f / v;
    }

#pragma unroll
  for (int i = 0; i < 4; ++i)
#pragma unroll
    for (int j = 0; j < 4; ++j)
#pragma unroll
      for (int r = 0; r < 4; ++r)
        qkv[(size_t)(b * 256 + q0 + i * 16 + tq * 4 + r) * 1536 + h * 64 +
            j * 16 + tr] = f2b(o[i][j][r] * pl[i][r]);
}

// ---- fused LN1+LN2: x = LN2(LN1(x + d1) + cavec16[b]) ---------------------
__global__ __launch_bounds__(256) void ln12_kernel(
    ushort* __restrict__ x16, const uint* __restrict__ d1,
    const uint* __restrict__ cavec, const float* __restrict__ s1,
    const float* __restrict__ b1, const float* __restrict__ s2,
    const float* __restrict__ b2p) {
  const int r = blockIdx.x, t = threadIdx.x;
  const int lane = t & 63, wv = t >> 6;
  uint* xr = (uint*)x16 + (size_t)r * 256;
  uint xu = xr[t];
  uint du = d1[(size_t)r * 768 + t];
  float v0 = blo(xu) + blo(du), v1 = bhi(xu) + bhi(du);
  __shared__ float redA[4][2], redB[4][2];
  float sm = v0 + v1, sq = v0 * v0 + v1 * v1;
#pragma unroll
  for (int o = 32; o > 0; o >>= 1) {
    sm += __shfl_xor(sm, o, 64);
    sq += __shfl_xor(sq, o, 64);
  }
  if (lane == 0) {
    redA[wv][0] = sm;
    redA[wv][1] = sq;
  }
  __syncthreads();
  sm = redA[0][0] + redA[1][0] + redA[2][0] + redA[3][0];
  sq = redA[0][1] + redA[1][1] + redA[2][1] + redA[3][1];
  float mean = sm * (1.f / 512.f);
  float var = sq * (1.f / 512.f) - mean * mean;
  float rs = rsqrtf(var + 1e-5f);
  float2 sa = ((const float2*)s1)[t];
  float2 ba = ((const float2*)b1)[t];
  uint cu = cavec[(size_t)(r >> 8) * 256 + t];
  float w0 = (v0 - mean) * rs * sa.x + ba.x + blo(cu);
  float w1 = (v1 - mean) * rs * sa.y + ba.y + bhi(cu);
  sm = w0 + w1;
  sq = w0 * w0 + w1 * w1;
#pragma unroll
  for (int o = 32; o > 0; o >>= 1) {
    sm += __shfl_xor(sm, o, 64);
    sq += __shfl_xor(sq, o, 64);
  }
  if (lane == 0) {
    redB[wv][0] = sm;
    redB[wv][1] = sq;
  }
  __syncthreads();
  sm = redB[0][0] + redB[1][0] + redB[2][0] + redB[3][0];
  sq = redB[0][1] + redB[1][1] + redB[2][1] + redB[3][1];
  mean = sm * (1.f / 512.f);
  var = sq * (1.f / 512.f) - mean * mean;
  rs = rsqrtf(var + 1e-5f);
  float2 sb = ((const float2*)s2)[t];
  float2 bb = ((const float2*)b2p)[t];
  float y0 = (w0 - mean) * rs * sb.x + bb.x;
  float y1 = (w1 - mean) * rs * sb.y + bb.y;
  xr[t] = pack2(y0, y1);
}

// -------- LayerNorm: x16 = bf16(LN(x16 + delta) * sc + bi), in place --------
__global__ __launch_bounds__(256) void ln_kernel(
    ushort* __restrict__ x16, const uint* __restrict__ delta, int DsU,
    const float* __restrict__ sc, const float* __restrict__ bi) {
  const int r = blockIdx.x, t = threadIdx.x;
  const int lane = t & 63, wv = t >> 6;
  uint* xr = (uint*)x16 + (size_t)r * 256;
  uint xu = xr[t];
  uint du = delta[(size_t)r * DsU + t];
  float v0 = blo(xu) + blo(du), v1 = bhi(xu) + bhi(du);
  float sm = v0 + v1, sq = v0 * v0 + v1 * v1;
#pragma unroll
  for (int o = 32; o > 0; o >>= 1) {
    sm += __shfl_xor(sm, o, 64);
    sq += __shfl_xor(sq, o, 64);
  }
  __shared__ float red[4][2];
  if (lane == 0) {
    red[wv][0] = sm;
    red[wv][1] = sq;
  }
  __syncthreads();
  sm = red[0][0] + red[1][0] + red[2][0] + red[3][0];
  sq = red[0][1] + red[1][1] + red[2][1] + red[3][1];
  float mean = sm * (1.f / 512.f);
  float var = sq * (1.f / 512.f) - mean * mean;
  float rs = rsqrtf(var + 1e-5f);
  float2 s2 = ((const float2*)sc)[t];
  float2 b2 = ((const float2*)bi)[t];
  float y0 = (v0 - mean) * rs * s2.x + b2.x;
  float y1 = (v1 - mean) * rs * s2.y + b2.y;
  xr[t] = pack2(y0, y1);
}

extern "C" void kernel_launch(void* const* d_in, const int* in_sizes, int n_in,
                              void* d_out, int out_size, void* d_ws,
                              size_t ws_size, hipStream_t stream) {
  (void)in_sizes; (void)n_in; (void)out_size; (void)ws_size;
  const float* z = (const float*)d_in[0];
  const int* tgt = (const int*)d_in[1];
  const float* emb = (const float*)d_in[2];
  const float* pos = (const float*)d_in[3];
  const float* projw = (const float*)d_in[4];
  const float* projb = (const float*)d_in[5];
  const float* saw = (const float*)d_in[6];
  const float* sab = (const float*)d_in[7];
  const float* saow = (const float*)d_in[8];
  const float* saob = (const float*)d_in[9];
  const float* caw = (const float*)d_in[10];
  const float* cab = (const float*)d_in[11];
  const float* caow = (const float*)d_in[12];
  const float* caob = (const float*)d_in[13];
  const float* ln1s = (const float*)d_in[14];
  const float* ln1b = (const float*)d_in[15];
  const float* ln2s = (const float*)d_in[16];
  const float* ln2b = (const float*)d_in[17];
  const float* ln3s = (const float*)d_in[18];
  const float* ln3b = (const float*)d_in[19];
  const float* ff1w = (const float*)d_in[20];
  const float* ff1b = (const float*)d_in[21];
  const float* ff2w = (const float*)d_in[22];
  const float* ff2b = (const float*)d_in[23];
  const float* fcw = (const float*)d_in[24];
  const float* fcb = (const float*)d_in[25];

  // dynamic LDS for gemm256: main loop 128 KiB + padded epilogue = 139264 B
  const int SHB = 139264;
  static bool s_attr = false;
  if (!s_attr) {
    s_attr = true;
    (void)hipFuncSetAttribute(reinterpret_cast<const void*>(gemm256<0>),
                              hipFuncAttributeMaxDynamicSharedMemorySize, SHB);
    (void)hipFuncSetAttribute(reinterpret_cast<const void*>(gemm256<1>),
                              hipFuncAttributeMaxDynamicSharedMemorySize, SHB);
    (void)hipFuncSetAttribute(reinterpret_cast<const void*>(gemm256<2>),
                              hipFuncAttributeMaxDynamicSharedMemorySize, SHB);
    (void)hipFuncSetAttribute(reinterpret_cast<const void*>(gemm256<4>),
                              hipFuncAttributeMaxDynamicSharedMemorySize, SHB);
  }

  // workspace carve — TOTAL ~103 MiB:
  // [0,16M)    x16 bf16 residual
  // [16M,64M)  qkv 48M (attn in-place; out-proj delta in dead k-slice);
  //            FF phase: hbuf 32M + fdel 16M
  // [64M,66M)  bf16 smalls: z16(128x512) memv16(128x512) cav16(6x128x512)
  //            cavec16(6x128x512) — rows 64..127 are junk (M padded to 128)
  // [66M,~103M) bf16 weights (converted once per launch)
  char* w8 = (char*)d_ws;
  ushort* x16 = (ushort*)w8;
  ushort* qkv = (ushort*)(w8 + (16u << 20));
  ushort* hbuf = qkv;
  ushort* fdel = (ushort*)(w8 + (48u << 20));
  ushort* z16 = (ushort*)(w8 + (64u << 20));
  ushort* memv16 = z16 + 128 * 512;
  ushort* cav16 = memv16 + 128 * 512;
  ushort* cavec16 = cav16 + (size_t)L_ * 128 * 512;
  ushort* wsaw = (ushort*)(w8 + (66u << 20));
  ushort* wsaow = wsaw + (size_t)L_ * 1536 * 512;
  ushort* wff1 = wsaow + (size_t)L_ * 512 * 512;
  ushort* wff2 = wff1 + (size_t)L_ * 2048 * 512;
  ushort* wfcw = wff2 + (size_t)L_ * 512 * 2048;

  // one-time weight conversions (fp32 -> bf16)
  conv_kernel<<<(L_ * 1536 * 512) / 512, 256, 0, stream>>>(saw, wsaw);
  conv_kernel<<<(L_ * 512 * 512) / 512, 256, 0, stream>>>(saow, wsaow);
  conv_kernel<<<(L_ * 2048 * 512) / 512, 256, 0, stream>>>(ff1w, wff1);
  conv_kernel<<<(L_ * 512 * 2048) / 512, 256, 0, stream>>>(ff2w, wff2);
  conv_kernel<<<(V_ * 512) / 512, 256, 0, stream>>>(fcw, wfcw);
  conv_kernel<<<(B_ * 512) / 512, 256, 0, stream>>>(z, z16);

  embed_kernel<<<16384, 256, 0, stream>>>(tgt, emb, pos, x16);

  // collapsed cross-attention (kv len 1) via padded-M MFMA, all batched:
  // memv16 = z16 . projw^T + projb
  gemm_btf<<<dim3(4, 1, 1), 256, 0, stream>>>(z16, 0, projw, 0, projb, 0,
                                              memv16, 0, 512, 512, 512, 512, 512);
  // cav16[l] = memv16 . Wv_l^T + bv_l
  gemm_btf<<<dim3(4, 1, L_), 256, 0, stream>>>(
      memv16, 0, caw + 1024 * 512, (long)1536 * 512, cab + 1024, 1536, cav16,
      (long)128 * 512, 512, 512, 512, 512, 512);
  // cavec16[l] = cav16[l] . Wo_l^T + bo_l
  gemm_btf<<<dim3(4, 1, L_), 256, 0, stream>>>(
      cav16, (long)128 * 512, caow, (long)512 * 512, caob, 512, cavec16,
      (long)128 * 512, 512, 512, 512, 512, 512);

  for (int i = 0; i < L_; ++i) {
    // QKV (+ Q pre-scale): qkv = x16 . sa_w^T + sa_b
    gemm256<4><<<dim3(6, 64), 512, SHB, stream>>>(
        x16, wsaw + (size_t)i * 1536 * 512, sab + i * 1536, qkv, 1536, 512,
        512, 512, 1536);
    attn_mfma<<<dim3(2, H_, B_), 128, 0, stream>>>(qkv);
    // out-proj -> dead k-slice
    gemm256<0><<<dim3(2, 64), 512, SHB, stream>>>(
        qkv, wsaow + (size_t)i * 512 * 512, saob + i * 512, qkv + 512, 512,
        512, 1536, 512, 1536);
    // fused LN1 + cross-attn add + LN2
    ln12_kernel<<<16384, 256, 0, stream>>>(
        x16, (const uint*)(qkv + 512), (const uint*)(cavec16 + (size_t)i * 128 * 512),
        ln1s + i * 512, ln1b + i * 512, ln2s + i * 512, ln2b + i * 512);
    // FFN split into two DFF=1024 chunks
    gemm256<1><<<dim3(4, 64), 512, SHB, stream>>>(
        x16, wff1 + (size_t)i * 2048 * 512, ff1b + i * 2048, hbuf, 1024, 512,
        512, 512, 1024);
    gemm256<0><<<dim3(2, 64), 512, SHB, stream>>>(
        hbuf, wff2 + (size_t)i * 512 * 2048, ff2b + i * 512, fdel, 512, 1024,
        1024, 2048, 512);
    gemm256<1><<<dim3(4, 64), 512, SHB, stream>>>(
        x16, wff1 + ((size_t)i * 2048 + 1024) * 512, ff1b + i * 2048 + 1024,
        hbuf, 1024, 512, 512, 512, 1024);
    gemm256<2><<<dim3(2, 64), 512, SHB, stream>>>(
        hbuf, wff2 + (size_t)i * 512 * 2048 + 1024, (const float*)0, fdel, 512,
        1024, 1024, 2048, 512);
    ln_kernel<<<16384, 256, 0, stream>>>(x16, (const uint*)fdel, 256,
                                         ln3s + i * 512, ln3b + i * 512);
  }
  gemm_bt<3><<<dim3(1, 128), 256, 0, stream>>>(x16, wfcw, fcb, d_out, 128, 512,
                                               512, 512, 128);
}

// Round 3
// 1818.846 us; speedup vs baseline: 1.0463x; 1.0463x over previous
//
#include <hip/hip_runtime.h>

typedef unsigned int uint;
typedef unsigned short ushort;

typedef __attribute__((ext_vector_type(8))) __bf16 bf16x8;
typedef __attribute__((ext_vector_type(4))) float f32x4;

#define B_ 64
#define S_ 256
#define D_ 512
#define H_ 8
#define DFF_ 2048
#define V_ 128
#define L_ 6
#define BS_ (B_ * S_)

__device__ __forceinline__ float blo(uint u) { return __uint_as_float(u << 16); }
__device__ __forceinline__ float bhi(uint u) { return __uint_as_float(u & 0xffff0000u); }
__device__ __forceinline__ float b2f(ushort u) { return __uint_as_float(((uint)u) << 16); }
__device__ __forceinline__ ushort f2b(float f) {
  uint u = __float_as_uint(f);
  return (ushort)((u + 0x7fffu + ((u >> 16) & 1u)) >> 16);  // RTNE
}
__device__ __forceinline__ uint pack2(float a, float b) {
  return (uint)f2b(a) | ((uint)f2b(b) << 16);
}

#define GLOAD16(gp, lp)                                                        \
  __builtin_amdgcn_global_load_lds(                                            \
      (const __attribute__((address_space(1))) void*)(gp),                     \
      (__attribute__((address_space(3))) void*)(lp), 16, 0, 0)

// -------- fp32 -> bf16 bulk conversion (one-time per launch) ---------------
__global__ __launch_bounds__(256) void conv_kernel(const float* __restrict__ src,
                                                   ushort* __restrict__ dst) {
  size_t p = (size_t)blockIdx.x * 256 + threadIdx.x;
  float2 v = ((const float2*)src)[p];
  ((uint*)dst)[p] = pack2(v.x, v.y);
}

// -------- embedding: x16 = bf16(emb[tgt] + pos); emb/pos fp32 ---------------
__global__ __launch_bounds__(256) void embed_kernel(
    const int* __restrict__ tgt, const float* __restrict__ emb,
    const float* __restrict__ pos, ushort* __restrict__ x16) {
  int p = blockIdx.x * 256 + threadIdx.x;
  int row = p >> 8;
  int d2 = p & 255;
  int s = row & (S_ - 1);
  int tok = tgt[row];
  float2 e = ((const float2*)emb)[tok * 256 + d2];
  float2 pp = ((const float2*)pos)[s * 256 + d2];
  ((uint*)x16)[p] = pack2(e.x + pp.x, e.y + pp.y);
}

// --- MFMA GEMM (m97 structure): C = A[.,K](As) . W_bf16(Ws)[N][K]^T --------
// MODE 0: bf16(acc+bias)  1: relu  2: bf16 C+=acc  3: fp32 acc+bias
// MODE 4: bf16(acc+bias), cols<512 scaled by log2(e)/8 (Q pre-scale for attn)
// T1 XCD swizzle: consecutive linear block ids round-robin across the 8 XCDs
// (each with a private 4MiB L2). Remap so XCD k owns a CONTIGUOUS lid range
// = a set of full A-row-panels (all column-blocks of each panel on one XCD).
// Per-XCD L2 footprint: <=16 panels x 128KB + full W (<=1.6MB) <= 4MB.
// Requires gridDim.x*gridDim.y % 8 == 0 (all call sites satisfy this).
template <int MODE>
__global__ __launch_bounds__(256) void gemm_bt(
    const ushort* __restrict__ A, const ushort* __restrict__ W,
    const float* __restrict__ bias, void* __restrict__ Cv, int N, int K,
    int As, int Ws, int Cs) {
  __shared__ ushort la[128 * 32];
  __shared__ ushort lb[128 * 32];
  const int tid = threadIdx.x;
  const int wv = tid >> 6, lane = tid & 63;

  // bijective XCD-aware block swizzle (T1)
  const int nwg = gridDim.x * gridDim.y;
  int lid = blockIdx.x + gridDim.x * blockIdx.y;
  lid = (lid & 7) * (nwg >> 3) + (lid >> 3);
  const int bx = lid % gridDim.x;
  const int by = lid / gridDim.x;
  const int m0 = by << 7, n0 = bx << 7;

  const int wm = (wv >> 1) << 6, wn = (wv & 1) << 6;
  const int tr = lane & 15, tq = lane >> 4;

  const int lin0 = wv * 1024 + lane * 8;
  const int lin1 = lin0 + 512;
  const int am0 = lin0 >> 5, ac0 = lin0 & 31;
  const int am1 = lin1 >> 5, ac1 = lin1 & 31;

  const ushort* pa0 = A + (size_t)(m0 + am0) * As + ac0;
  const ushort* pa1 = A + (size_t)(m0 + am1) * As + ac1;
  const ushort* pb0 = W + (size_t)(n0 + am0) * Ws + ac0;
  const ushort* pb1 = W + (size_t)(n0 + am1) * Ws + ac1;
  ushort* la0 = &la[wv * 1024];
  ushort* la1 = &la[wv * 1024 + 512];
  ushort* lb0 = &lb[wv * 1024];
  ushort* lb1 = &lb[wv * 1024 + 512];

  f32x4 acc[4][4];
#pragma unroll
  for (int i = 0; i < 4; ++i)
#pragma unroll
    for (int j = 0; j < 4; ++j) acc[i][j] = (f32x4)(0.f);

  const int KT = K >> 5;
  for (int kt = 0; kt < KT; ++kt) {
    const int kb = kt << 5;
    GLOAD16(pa0 + kb, la0);
    GLOAD16(pa1 + kb, la1);
    GLOAD16(pb0 + kb, lb0);
    GLOAD16(pb1 + kb, lb1);
    __syncthreads();
    bf16x8 av[4], bv[4];
#pragma unroll
    for (int i = 0; i < 4; ++i)
      av[i] = *(const bf16x8*)&la[(wm + i * 16 + tr) * 32 + tq * 8];
#pragma unroll
    for (int j = 0; j < 4; ++j)
      bv[j] = *(const bf16x8*)&lb[(wn + j * 16 + tr) * 32 + tq * 8];
#pragma unroll
    for (int i = 0; i < 4; ++i)
#pragma unroll
      for (int j = 0; j < 4; ++j)
        acc[i][j] =
            __builtin_amdgcn_mfma_f32_16x16x32_bf16(av[i], bv[j], acc[i][j], 0, 0, 0);
    __syncthreads();
  }

#pragma unroll
  for (int j = 0; j < 4; ++j) {
    const int gn = n0 + wn + j * 16 + tr;
    float bj = 0.f;
    if (MODE != 2) bj = bias[gn];
    float scl = 1.f;
    if (MODE == 4) scl = (gn < 512) ? 0.18033688011112042f : 1.f;
#pragma unroll
    for (int i = 0; i < 4; ++i) {
      const int gmb = m0 + wm + i * 16 + tq * 4;
#pragma unroll
      for (int r = 0; r < 4; ++r) {
        const size_t idx = (size_t)(gmb + r) * Cs + gn;
        float v = acc[i][j][r] + bj;
        if (MODE == 1) v = fmaxf(v, 0.f);
        if (MODE == 4) v *= scl;
        if (MODE == 3)
          ((float*)Cv)[idx] = v;
        else if (MODE == 2) {
          ushort* C = (ushort*)Cv;
          C[idx] = f2b(b2f(C[idx]) + acc[i][j][r]);
        } else
          ((ushort*)Cv)[idx] = f2b(v);
      }
    }
  }
}

// --- batched MFMA GEMM, W fp32 converted during staging (Round-4-verified) --
// C_z = A_z[.,K](As) . W_z(Ws)[N][K]^T + bias_z ; z = blockIdx.z
__global__ __launch_bounds__(256) void gemm_btf(
    const ushort* __restrict__ A0, long zA, const float* __restrict__ W0,
    long zW, const float* __restrict__ bias0, long zb, ushort* __restrict__ C0,
    long zC, int N, int K, int As, int Ws, int Cs) {
  const int zz = blockIdx.z;
  const ushort* A = A0 + zA * zz;
  const float* W = W0 + zW * zz;
  const float* bias = bias0 + zb * zz;
  ushort* C = C0 + zC * zz;

  __shared__ ushort la[128 * 32];
  __shared__ ushort lb[128 * 32];
  const int tid = threadIdx.x;
  const int wv = tid >> 6, lane = tid & 63;
  const int m0 = blockIdx.y << 7, n0 = blockIdx.x << 7;
  const int wm = (wv >> 1) << 6, wn = (wv & 1) << 6;
  const int tr = lane & 15, tq = lane >> 4;

  const int lin0 = wv * 1024 + lane * 8;
  const int lin1 = lin0 + 512;
  const int am0 = lin0 >> 5, ac0 = lin0 & 31;
  const int am1 = lin1 >> 5, ac1 = lin1 & 31;

  const ushort* pa0 = A + (size_t)(m0 + am0) * As + ac0;
  const ushort* pa1 = A + (size_t)(m0 + am1) * As + ac1;
  const float* pb0 = W + (size_t)(n0 + am0) * Ws + ac0;
  const float* pb1 = W + (size_t)(n0 + am1) * Ws + ac1;

  f32x4 acc[4][4];
#pragma unroll
  for (int i = 0; i < 4; ++i)
#pragma unroll
    for (int j = 0; j < 4; ++j) acc[i][j] = (f32x4)(0.f);

  const int KT = K >> 5;
  for (int kt = 0; kt < KT; ++kt) {
    const int kb = kt << 5;
    uint4 ra0 = *(const uint4*)(pa0 + kb);
    uint4 ra1 = *(const uint4*)(pa1 + kb);
    float4 f00 = *(const float4*)(pb0 + kb);
    float4 f01 = *(const float4*)(pb0 + kb + 4);
    float4 f10 = *(const float4*)(pb1 + kb);
    float4 f11 = *(const float4*)(pb1 + kb + 4);
    uint4 rb0 = make_uint4(pack2(f00.x, f00.y), pack2(f00.z, f00.w),
                           pack2(f01.x, f01.y), pack2(f01.z, f01.w));
    uint4 rb1 = make_uint4(pack2(f10.x, f10.y), pack2(f10.z, f10.w),
                           pack2(f11.x, f11.y), pack2(f11.z, f11.w));
    __syncthreads();
    *(uint4*)&la[lin0] = ra0;
    *(uint4*)&la[lin1] = ra1;
    *(uint4*)&lb[lin0] = rb0;
    *(uint4*)&lb[lin1] = rb1;
    __syncthreads();
    bf16x8 av[4], bv[4];
#pragma unroll
    for (int i = 0; i < 4; ++i)
      av[i] = *(const bf16x8*)&la[(wm + i * 16 + tr) * 32 + tq * 8];
#pragma unroll
    for (int j = 0; j < 4; ++j)
      bv[j] = *(const bf16x8*)&lb[(wn + j * 16 + tr) * 32 + tq * 8];
#pragma unroll
    for (int i = 0; i < 4; ++i)
#pragma unroll
      for (int j = 0; j < 4; ++j)
        acc[i][j] =
            __builtin_amdgcn_mfma_f32_16x16x32_bf16(av[i], bv[j], acc[i][j], 0, 0, 0);
  }

#pragma unroll
  for (int j = 0; j < 4; ++j) {
    const int gn = n0 + wn + j * 16 + tr;
    const float bj = bias[gn];
#pragma unroll
    for (int i = 0; i < 4; ++i) {
      const int gmb = m0 + wm + i * 16 + tq * 4;
#pragma unroll
      for (int r = 0; r < 4; ++r)
        C[(size_t)(gmb + r) * Cs + gn] = f2b(acc[i][j][r] + bj);
    }
  }
}

// ---------------- MFMA causal attention v3 ----------------
// grid (2, H, B), 128 threads (2 waves). Wave g owns q-chunk qc=2*qp+g.
// K staged [key][d]; V staged TRANSPOSED [d][key] so PV B-frags are b128.
// Q pre-scaled by log2(e)/8 in QKV GEMM. In-place output over q-slice.
// P relay is per-wave LDS (in-order LDS pipe) -> no barrier between P and PV.
__global__ __launch_bounds__(128) void attn_mfma(ushort* __restrict__ qkv) {
  __shared__ ushort lk[64 * 72];      // K chunk  [key][64+8]
  __shared__ ushort lvT[64 * 72];     // V^T      [d][64+8]
  __shared__ ushort lp[2 * 64 * 72];  // per-wave P [qrow][64+8]
  const int qp = blockIdx.x, h = blockIdx.y, b = blockIdx.z;
  const int tid = threadIdx.x;
  const int g = tid >> 6, lane = tid & 63;
  const int tr = lane & 15, tq = lane >> 4;
  const int qc = qp * 2 + g;
  const int q0 = qc << 6;
  ushort* myp = &lp[g * 64 * 72];

  bf16x8 qf[4][2];
#pragma unroll
  for (int i = 0; i < 4; ++i)
#pragma unroll
    for (int s = 0; s < 2; ++s)
      qf[i][s] = *(const bf16x8*)(qkv +
                                  (size_t)(b * 256 + q0 + i * 16 + tr) * 1536 +
                                  h * 64 + s * 32 + tq * 8);

  f32x4 o[4][4];
  float pl[4][4];
#pragma unroll
  for (int i = 0; i < 4; ++i)
#pragma unroll
    for (int j = 0; j < 4; ++j) {
      o[i][j] = (f32x4)(0.f);
      pl[i][j] = 0.f;
    }

  const int key = tid >> 1, half = tid & 1;
  const int cmax = qp * 2 + 1;
  for (int c = 0; c <= cmax; ++c) {
    __syncthreads();  // protect prior chunk's lk/lvT reads
    const ushort* gk =
        qkv + (size_t)(b * 256 + c * 64 + key) * 1536 + 512 + h * 64 + half * 32;
#pragma unroll
    for (int u = 0; u < 4; ++u)
      *(uint4*)&lk[key * 72 + half * 32 + u * 8] = *(const uint4*)(gk + u * 8);
    ushort vloc[32];
#pragma unroll
    for (int u = 0; u < 4; ++u)
      *(uint4*)&vloc[u * 8] = *(const uint4*)(gk + 512 + u * 8);
#pragma unroll
    for (int dd = 0; dd < 32; ++dd)
      lvT[(half * 32 + dd) * 72 + key] = vloc[dd];
    __syncthreads();

    if (c <= qc) {
      // S = Q . K^T
      f32x4 Sv[4][4];
#pragma unroll
      for (int i = 0; i < 4; ++i)
#pragma unroll
        for (int j = 0; j < 4; ++j) Sv[i][j] = (f32x4)(0.f);
      bf16x8 kf[4][2];
#pragma unroll
      for (int j = 0; j < 4; ++j)
#pragma unroll
        for (int s = 0; s < 2; ++s)
          kf[j][s] = *(const bf16x8*)&lk[(j * 16 + tr) * 72 + s * 32 + tq * 8];
#pragma unroll
      for (int i = 0; i < 4; ++i)
#pragma unroll
        for (int j = 0; j < 4; ++j) {
          Sv[i][j] = __builtin_amdgcn_mfma_f32_16x16x32_bf16(qf[i][0], kf[j][0],
                                                             Sv[i][j], 0, 0, 0);
          Sv[i][j] = __builtin_amdgcn_mfma_f32_16x16x32_bf16(qf[i][1], kf[j][1],
                                                             Sv[i][j], 0, 0, 0);
        }
      // exp2 (Q pre-scaled) + causal mask + partial rowsums + P -> own LDS
      const bool diag = (c == qc);
#pragma unroll
      for (int i = 0; i < 4; ++i)
#pragma unroll
        for (int j = 0; j < 4; ++j)
#pragma unroll
          for (int r = 0; r < 4; ++r) {
            float e = exp2f(Sv[i][j][r]);
            if (diag && (j * 16 + tr) > (i * 16 + tq * 4 + r)) e = 0.f;
            pl[i][r] += e;
            myp[(i * 16 + tq * 4 + r) * 72 + j * 16 + tr] =
                (ushort)(__float_as_uint(e) >> 16);  // trunc: P in [0,1]
          }
      // O += P . V  (same-wave LDS RAW: in-order DS pipe, no barrier)
#pragma unroll
      for (int s = 0; s < 2; ++s) {
        bf16x8 vf[4], af[4];
#pragma unroll
        for (int jn = 0; jn < 4; ++jn)
          vf[jn] = *(const bf16x8*)&lvT[(jn * 16 + tr) * 72 + s * 32 + tq * 8];
#pragma unroll
        for (int im = 0; im < 4; ++im)
          af[im] = *(const bf16x8*)&myp[(im * 16 + tr) * 72 + s * 32 + tq * 8];
#pragma unroll
        for (int im = 0; im < 4; ++im)
#pragma unroll
          for (int jn = 0; jn < 4; ++jn)
            o[im][jn] = __builtin_amdgcn_mfma_f32_16x16x32_bf16(af[im], vf[jn],
                                                                o[im][jn], 0, 0, 0);
      }
    }
  }

#pragma unroll
  for (int i = 0; i < 4; ++i)
#pragma unroll
    for (int r = 0; r < 4; ++r) {
      float v = pl[i][r];
      v += __shfl_xor(v, 1, 64);
      v += __shfl_xor(v, 2, 64);
      v += __shfl_xor(v, 4, 64);
      v += __shfl_xor(v, 8, 64);
      pl[i][r] = 1.f / v;
    }

#pragma unroll
  for (int i = 0; i < 4; ++i)
#pragma unroll
    for (int j = 0; j < 4; ++j)
#pragma unroll
      for (int r = 0; r < 4; ++r)
        qkv[(size_t)(b * 256 + q0 + i * 16 + tq * 4 + r) * 1536 + h * 64 +
            j * 16 + tr] = f2b(o[i][j][r] * pl[i][r]);
}

// ---- fused LN1+LN2: x = LN2(LN1(x + d1) + cavec16[b]) ---------------------
__global__ __launch_bounds__(256) void ln12_kernel(
    ushort* __restrict__ x16, const uint* __restrict__ d1,
    const uint* __restrict__ cavec, const float* __restrict__ s1,
    const float* __restrict__ b1, const float* __restrict__ s2,
    const float* __restrict__ b2p) {
  const int r = blockIdx.x, t = threadIdx.x;
  const int lane = t & 63, wv = t >> 6;
  uint* xr = (uint*)x16 + (size_t)r * 256;
  uint xu = xr[t];
  uint du = d1[(size_t)r * 768 + t];
  float v0 = blo(xu) + blo(du), v1 = bhi(xu) + bhi(du);
  __shared__ float redA[4][2], redB[4][2];
  float sm = v0 + v1, sq = v0 * v0 + v1 * v1;
#pragma unroll
  for (int o = 32; o > 0; o >>= 1) {
    sm += __shfl_xor(sm, o, 64);
    sq += __shfl_xor(sq, o, 64);
  }
  if (lane == 0) {
    redA[wv][0] = sm;
    redA[wv][1] = sq;
  }
  __syncthreads();
  sm = redA[0][0] + redA[1][0] + redA[2][0] + redA[3][0];
  sq = redA[0][1] + redA[1][1] + redA[2][1] + redA[3][1];
  float mean = sm * (1.f / 512.f);
  float var = sq * (1.f / 512.f) - mean * mean;
  float rs = rsqrtf(var + 1e-5f);
  float2 sa = ((const float2*)s1)[t];
  float2 ba = ((const float2*)b1)[t];
  uint cu = cavec[(size_t)(r >> 8) * 256 + t];
  float w0 = (v0 - mean) * rs * sa.x + ba.x + blo(cu);
  float w1 = (v1 - mean) * rs * sa.y + ba.y + bhi(cu);
  sm = w0 + w1;
  sq = w0 * w0 + w1 * w1;
#pragma unroll
  for (int o = 32; o > 0; o >>= 1) {
    sm += __shfl_xor(sm, o, 64);
    sq += __shfl_xor(sq, o, 64);
  }
  if (lane == 0) {
    redB[wv][0] = sm;
    redB[wv][1] = sq;
  }
  __syncthreads();
  sm = redB[0][0] + redB[1][0] + redB[2][0] + redB[3][0];
  sq = redB[0][1] + redB[1][1] + redB[2][1] + redB[3][1];
  mean = sm * (1.f / 512.f);
  var = sq * (1.f / 512.f) - mean * mean;
  rs = rsqrtf(var + 1e-5f);
  float2 sb = ((const float2*)s2)[t];
  float2 bb = ((const float2*)b2p)[t];
  float y0 = (w0 - mean) * rs * sb.x + bb.x;
  float y1 = (w1 - mean) * rs * sb.y + bb.y;
  xr[t] = pack2(y0, y1);
}

// -------- LayerNorm: x16 = bf16(LN(x16 + delta) * sc + bi), in place --------
__global__ __launch_bounds__(256) void ln_kernel(
    ushort* __restrict__ x16, const uint* __restrict__ delta, int DsU,
    const float* __restrict__ sc, const float* __restrict__ bi) {
  const int r = blockIdx.x, t = threadIdx.x;
  const int lane = t & 63, wv = t >> 6;
  uint* xr = (uint*)x16 + (size_t)r * 256;
  uint xu = xr[t];
  uint du = delta[(size_t)r * DsU + t];
  float v0 = blo(xu) + blo(du), v1 = bhi(xu) + bhi(du);
  float sm = v0 + v1, sq = v0 * v0 + v1 * v1;
#pragma unroll
  for (int o = 32; o > 0; o >>= 1) {
    sm += __shfl_xor(sm, o, 64);
    sq += __shfl_xor(sq, o, 64);
  }
  __shared__ float red[4][2];
  if (lane == 0) {
    red[wv][0] = sm;
    red[wv][1] = sq;
  }
  __syncthreads();
  sm = red[0][0] + red[1][0] + red[2][0] + red[3][0];
  sq = red[0][1] + red[1][1] + red[2][1] + red[3][1];
  float mean = sm * (1.f / 512.f);
  float var = sq * (1.f / 512.f) - mean * mean;
  float rs = rsqrtf(var + 1e-5f);
  float2 s2 = ((const float2*)sc)[t];
  float2 b2 = ((const float2*)bi)[t];
  float y0 = (v0 - mean) * rs * s2.x + b2.x;
  float y1 = (v1 - mean) * rs * s2.y + b2.y;
  xr[t] = pack2(y0, y1);
}

extern "C" void kernel_launch(void* const* d_in, const int* in_sizes, int n_in,
                              void* d_out, int out_size, void* d_ws,
                              size_t ws_size, hipStream_t stream) {
  (void)in_sizes; (void)n_in; (void)out_size; (void)ws_size;
  const float* z = (const float*)d_in[0];
  const int* tgt = (const int*)d_in[1];
  const float* emb = (const float*)d_in[2];
  const float* pos = (const float*)d_in[3];
  const float* projw = (const float*)d_in[4];
  const float* projb = (const float*)d_in[5];
  const float* saw = (const float*)d_in[6];
  const float* sab = (const float*)d_in[7];
  const float* saow = (const float*)d_in[8];
  const float* saob = (const float*)d_in[9];
  const float* caw = (const float*)d_in[10];
  const float* cab = (const float*)d_in[11];
  const float* caow = (const float*)d_in[12];
  const float* caob = (const float*)d_in[13];
  const float* ln1s = (const float*)d_in[14];
  const float* ln1b = (const float*)d_in[15];
  const float* ln2s = (const float*)d_in[16];
  const float* ln2b = (const float*)d_in[17];
  const float* ln3s = (const float*)d_in[18];
  const float* ln3b = (const float*)d_in[19];
  const float* ff1w = (const float*)d_in[20];
  const float* ff1b = (const float*)d_in[21];
  const float* ff2w = (const float*)d_in[22];
  const float* ff2b = (const float*)d_in[23];
  const float* fcw = (const float*)d_in[24];
  const float* fcb = (const float*)d_in[25];

  // workspace carve — TOTAL ~103 MiB:
  // [0,16M)    x16 bf16 residual
  // [16M,64M)  qkv 48M (attn in-place; out-proj delta in dead k-slice);
  //            FF phase: hbuf 32M + fdel 16M
  // [64M,66M)  bf16 smalls: z16(128x512) memv16(128x512) cav16(6x128x512)
  //            cavec16(6x128x512) — rows 64..127 are junk (M padded to 128)
  // [66M,~103M) bf16 weights (converted once per launch)
  char* w8 = (char*)d_ws;
  ushort* x16 = (ushort*)w8;
  ushort* qkv = (ushort*)(w8 + (16u << 20));
  ushort* hbuf = qkv;
  ushort* fdel = (ushort*)(w8 + (48u << 20));
  ushort* z16 = (ushort*)(w8 + (64u << 20));
  ushort* memv16 = z16 + 128 * 512;
  ushort* cav16 = memv16 + 128 * 512;
  ushort* cavec16 = cav16 + (size_t)L_ * 128 * 512;
  ushort* wsaw = (ushort*)(w8 + (66u << 20));
  ushort* wsaow = wsaw + (size_t)L_ * 1536 * 512;
  ushort* wff1 = wsaow + (size_t)L_ * 512 * 512;
  ushort* wff2 = wff1 + (size_t)L_ * 2048 * 512;
  ushort* wfcw = wff2 + (size_t)L_ * 512 * 2048;

  // one-time weight conversions (fp32 -> bf16)
  conv_kernel<<<(L_ * 1536 * 512) / 512, 256, 0, stream>>>(saw, wsaw);
  conv_kernel<<<(L_ * 512 * 512) / 512, 256, 0, stream>>>(saow, wsaow);
  conv_kernel<<<(L_ * 2048 * 512) / 512, 256, 0, stream>>>(ff1w, wff1);
  conv_kernel<<<(L_ * 512 * 2048) / 512, 256, 0, stream>>>(ff2w, wff2);
  conv_kernel<<<(V_ * 512) / 512, 256, 0, stream>>>(fcw, wfcw);
  conv_kernel<<<(B_ * 512) / 512, 256, 0, stream>>>(z, z16);

  embed_kernel<<<16384, 256, 0, stream>>>(tgt, emb, pos, x16);

  // collapsed cross-attention (kv len 1) via padded-M MFMA, all batched:
  // memv16 = z16 . projw^T + projb
  gemm_btf<<<dim3(4, 1, 1), 256, 0, stream>>>(z16, 0, projw, 0, projb, 0,
                                              memv16, 0, 512, 512, 512, 512, 512);
  // cav16[l] = memv16 . Wv_l^T + bv_l
  gemm_btf<<<dim3(4, 1, L_), 256, 0, stream>>>(
      memv16, 0, caw + 1024 * 512, (long)1536 * 512, cab + 1024, 1536, cav16,
      (long)128 * 512, 512, 512, 512, 512, 512);
  // cavec16[l] = cav16[l] . Wo_l^T + bo_l
  gemm_btf<<<dim3(4, 1, L_), 256, 0, stream>>>(
      cav16, (long)128 * 512, caow, (long)512 * 512, caob, 512, cavec16,
      (long)128 * 512, 512, 512, 512, 512, 512);

  for (int i = 0; i < L_; ++i) {
    // QKV (+ Q pre-scale): qkv = x16 . sa_w^T + sa_b
    gemm_bt<4><<<dim3(12, 128), 256, 0, stream>>>(
        x16, wsaw + (size_t)i * 1536 * 512, sab + i * 1536, qkv, 1536, 512, 512,
        512, 1536);
    attn_mfma<<<dim3(2, H_, B_), 128, 0, stream>>>(qkv);
    // out-proj -> dead k-slice
    gemm_bt<0><<<dim3(4, 128), 256, 0, stream>>>(
        qkv, wsaow + (size_t)i * 512 * 512, saob + i * 512, qkv + 512, 512, 512,
        1536, 512, 1536);
    // fused LN1 + cross-attn add + LN2
    ln12_kernel<<<16384, 256, 0, stream>>>(
        x16, (const uint*)(qkv + 512), (const uint*)(cavec16 + (size_t)i * 128 * 512),
        ln1s + i * 512, ln1b + i * 512, ln2s + i * 512, ln2b + i * 512);
    // FFN split into two DFF=1024 chunks
    gemm_bt<1><<<dim3(8, 128), 256, 0, stream>>>(
        x16, wff1 + (size_t)i * 2048 * 512, ff1b + i * 2048, hbuf, 1024, 512,
        512, 512, 1024);
    gemm_bt<0><<<dim3(4, 128), 256, 0, stream>>>(
        hbuf, wff2 + (size_t)i * 512 * 2048, ff2b + i * 512, fdel, 512, 1024,
        1024, 2048, 512);
    gemm_bt<1><<<dim3(8, 128), 256, 0, stream>>>(
        x16, wff1 + ((size_t)i * 2048 + 1024) * 512, ff1b + i * 2048 + 1024,
        hbuf, 1024, 512, 512, 512, 1024);
    gemm_bt<2><<<dim3(4, 128), 256, 0, stream>>>(
        hbuf, wff2 + (size_t)i * 512 * 2048 + 1024, (const float*)0, fdel, 512,
        1024, 1024, 2048, 512);
    ln_kernel<<<16384, 256, 0, stream>>>(x16, (const uint*)fdel, 256,
                                         ln3s + i * 512, ln3b + i * 512);
  }
  gemm_bt<3><<<dim3(1, 128), 256, 0, stream>>>(x16, wfcw, fcb, d_out, 128, 512,
                                               512, 512, 128);
}

// Round 6
// 1611.732 us; speedup vs baseline: 1.1808x; 1.1285x over previous
//
#include <hip/hip_runtime.h>

typedef unsigned int uint;
typedef unsigned short ushort;

typedef __attribute__((ext_vector_type(8))) __bf16 bf16x8;
typedef __attribute__((ext_vector_type(4))) float f32x4;

#define B_ 64
#define S_ 256
#define D_ 512
#define H_ 8
#define DFF_ 2048
#define V_ 128
#define L_ 6
#define BS_ (B_ * S_)

__device__ __forceinline__ float blo(uint u) { return __uint_as_float(u << 16); }
__device__ __forceinline__ float bhi(uint u) { return __uint_as_float(u & 0xffff0000u); }
__device__ __forceinline__ float b2f(ushort u) { return __uint_as_float(((uint)u) << 16); }
__device__ __forceinline__ ushort f2b(float f) {
  uint u = __float_as_uint(f);
  return (ushort)((u + 0x7fffu + ((u >> 16) & 1u)) >> 16);  // RTNE
}
__device__ __forceinline__ uint pack2(float a, float b) {
  return (uint)f2b(a) | ((uint)f2b(b) << 16);
}

#define GLOAD16(gp, lp)                                                        \
  __builtin_amdgcn_global_load_lds(                                            \
      (const __attribute__((address_space(1))) void*)(gp),                     \
      (__attribute__((address_space(3))) void*)(lp), 16, 0, 0)

// -------- fp32 -> bf16 bulk conversion (one-time per launch) ---------------
__global__ __launch_bounds__(256) void conv_kernel(const float* __restrict__ src,
                                                   ushort* __restrict__ dst) {
  size_t p = (size_t)blockIdx.x * 256 + threadIdx.x;
  float2 v = ((const float2*)src)[p];
  ((uint*)dst)[p] = pack2(v.x, v.y);
}

// -------- embedding: x16 = bf16(emb[tgt] + pos); emb/pos fp32 ---------------
__global__ __launch_bounds__(256) void embed_kernel(
    const int* __restrict__ tgt, const float* __restrict__ emb,
    const float* __restrict__ pos, ushort* __restrict__ x16) {
  int p = blockIdx.x * 256 + threadIdx.x;
  int row = p >> 8;
  int d2 = p & 255;
  int s = row & (S_ - 1);
  int tok = tgt[row];
  float2 e = ((const float2*)emb)[tok * 256 + d2];
  float2 pp = ((const float2*)pos)[s * 256 + d2];
  ((uint*)x16)[p] = pack2(e.x + pp.x, e.y + pp.y);
}

// === register-staged double-buffered BK=64 MFMA GEMM (T14 pattern) =========
// C = A[.,K](As) . W_bf16(Ws)[N][K]^T + bias. 128x128 tile, 4 waves.
// MODE 0: bf16(acc+bias)  1: relu  2: bf16 C+=acc  4: Q-prescale (cols<512)
// NO inline asm, NO global_load_lds: tile t+1 is loaded to REGISTERS at the
// top of iteration t (async vmem), consumed by ds_write AFTER the MFMA block
// -> the compiler-inserted vmcnt wait lands after ~400cy of compute, hiding
// the HBM/L2 latency that round-3 counters showed exposed (both pipes idle,
// MfmaUtil 21%). Buffer d^1 is written while only buffer d is read; the one
// end-of-iteration barrier orders it against the previous iteration's reads.
// LDS 64KB: la/lb [2 buf][2 ksub][128][32] ushort (2-way bank = free).
// T1 bijective XCD swizzle kept (round-3 verified: FETCH 69->20MB).
// Requires K%64==0, M%128==0, N%128==0, nwg%8==0.
template <int MODE>
__global__ __launch_bounds__(256) void gemm_rs(
    const ushort* __restrict__ A, const ushort* __restrict__ W,
    const float* __restrict__ bias, void* __restrict__ Cv, int N, int K,
    int As, int Ws, int Cs) {
  __shared__ ushort la[2][8192];  // [buf][ksub*4096 + row*32 + col]
  __shared__ ushort lb[2][8192];
  const int tid = threadIdx.x;
  const int wv = tid >> 6, lane = tid & 63;

  // bijective XCD-aware block swizzle (T1)
  const int nwg = gridDim.x * gridDim.y;
  int lid = blockIdx.x + gridDim.x * blockIdx.y;
  lid = (lid & 7) * (nwg >> 3) + (lid >> 3);
  const int bx = lid % gridDim.x;
  const int by = lid / gridDim.x;
  const int m0 = by << 7, n0 = bx << 7;

  const int wm = (wv >> 1) << 6, wn = (wv & 1) << 6;
  const int tr = lane & 15, tq = lane >> 4;

  // staging map (same as proven gemm_bt): thread covers 16B at LDS offset
  // lin0 and lin0+512 within each 4096-ushort k-sub-tile.
  const int lin0 = wv * 1024 + lane * 8;
  const int am0 = lin0 >> 5, ac0 = lin0 & 31;
  const int lin1 = lin0 + 512;
  const int am1 = lin1 >> 5, ac1 = lin1 & 31;

  const ushort* pa0 = A + (size_t)(m0 + am0) * As + ac0;
  const ushort* pa1 = A + (size_t)(m0 + am1) * As + ac1;
  const ushort* pb0 = W + (size_t)(n0 + am0) * Ws + ac0;
  const ushort* pb1 = W + (size_t)(n0 + am1) * Ws + ac1;

  f32x4 acc[4][4];
#pragma unroll
  for (int i = 0; i < 4; ++i)
#pragma unroll
    for (int j = 0; j < 4; ++j) acc[i][j] = (f32x4)(0.f);

  const int KT = K >> 6;  // BK = 64
  uint4 ra0, ra1, ra2, ra3, rb0, rb1, rb2, rb3;  // staged tile (static regs)

#define LOADR(t)                                                               \
  do {                                                                         \
    const int kb_ = (t) << 6;                                                  \
    ra0 = *(const uint4*)(pa0 + kb_);                                          \
    ra1 = *(const uint4*)(pa1 + kb_);                                          \
    ra2 = *(const uint4*)(pa0 + kb_ + 32);                                     \
    ra3 = *(const uint4*)(pa1 + kb_ + 32);                                     \
    rb0 = *(const uint4*)(pb0 + kb_);                                          \
    rb1 = *(const uint4*)(pb1 + kb_);                                          \
    rb2 = *(const uint4*)(pb0 + kb_ + 32);                                     \
    rb3 = *(const uint4*)(pb1 + kb_ + 32);                                     \
  } while (0)
#define WRITR(d)                                                               \
  do {                                                                         \
    *(uint4*)&la[d][lin0] = ra0;                                               \
    *(uint4*)&la[d][lin1] = ra1;                                               \
    *(uint4*)&la[d][4096 + lin0] = ra2;                                        \
    *(uint4*)&la[d][4096 + lin1] = ra3;                                        \
    *(uint4*)&lb[d][lin0] = rb0;                                               \
    *(uint4*)&lb[d][lin1] = rb1;                                               \
    *(uint4*)&lb[d][4096 + lin0] = rb2;                                        \
    *(uint4*)&lb[d][4096 + lin1] = rb3;                                        \
  } while (0)

  LOADR(0);
  WRITR(0);
  __syncthreads();

  for (int t = 0; t < KT; ++t) {
    const int d = t & 1;
    if (t + 1 < KT) LOADR(t + 1);  // issue next-tile loads (no wait yet)
    bf16x8 av[2][4], bv[2][4];
#pragma unroll
    for (int s = 0; s < 2; ++s) {
#pragma unroll
      for (int i = 0; i < 4; ++i)
        av[s][i] =
            *(const bf16x8*)&la[d][s * 4096 + (wm + i * 16 + tr) * 32 + tq * 8];
#pragma unroll
      for (int j = 0; j < 4; ++j)
        bv[s][j] =
            *(const bf16x8*)&lb[d][s * 4096 + (wn + j * 16 + tr) * 32 + tq * 8];
    }
#pragma unroll
    for (int s = 0; s < 2; ++s)
#pragma unroll
      for (int i = 0; i < 4; ++i)
#pragma unroll
        for (int j = 0; j < 4; ++j)
          acc[i][j] = __builtin_amdgcn_mfma_f32_16x16x32_bf16(
              av[s][i], bv[s][j], acc[i][j], 0, 0, 0);
    // consume staged regs AFTER compute: vmcnt wait sits here, latency hidden.
    // Writes target buf d^1 (not being read this iteration); barrier at end
    // of the previous iteration ordered them against its reads of buf d^1.
    if (t + 1 < KT) WRITR(d ^ 1);
    __syncthreads();
  }
#undef LOADR
#undef WRITR

#pragma unroll
  for (int j = 0; j < 4; ++j) {
    const int gn = n0 + wn + j * 16 + tr;
    float bj = 0.f;
    if (MODE != 2) bj = bias[gn];
    float scl = 1.f;
    if (MODE == 4) scl = (gn < 512) ? 0.18033688011112042f : 1.f;
#pragma unroll
    for (int i = 0; i < 4; ++i) {
      const int gmb = m0 + wm + i * 16 + tq * 4;
#pragma unroll
      for (int r = 0; r < 4; ++r) {
        const size_t idx = (size_t)(gmb + r) * Cs + gn;
        float v = acc[i][j][r] + bj;
        if (MODE == 1) v = fmaxf(v, 0.f);
        if (MODE == 4) v *= scl;
        if (MODE == 2) {
          ushort* C = (ushort*)Cv;
          C[idx] = f2b(b2f(C[idx]) + acc[i][j][r]);
        } else
          ((ushort*)Cv)[idx] = f2b(v);
      }
    }
  }
}

// --- MFMA GEMM (m97 structure + T1 swizzle), kept for final fc -------------
// MODE 3: fp32 acc+bias
template <int MODE>
__global__ __launch_bounds__(256) void gemm_bt(
    const ushort* __restrict__ A, const ushort* __restrict__ W,
    const float* __restrict__ bias, void* __restrict__ Cv, int N, int K,
    int As, int Ws, int Cs) {
  __shared__ ushort la[128 * 32];
  __shared__ ushort lb[128 * 32];
  const int tid = threadIdx.x;
  const int wv = tid >> 6, lane = tid & 63;

  const int nwg = gridDim.x * gridDim.y;
  int lid = blockIdx.x + gridDim.x * blockIdx.y;
  lid = (lid & 7) * (nwg >> 3) + (lid >> 3);
  const int bx = lid % gridDim.x;
  const int by = lid / gridDim.x;
  const int m0 = by << 7, n0 = bx << 7;

  const int wm = (wv >> 1) << 6, wn = (wv & 1) << 6;
  const int tr = lane & 15, tq = lane >> 4;

  const int lin0 = wv * 1024 + lane * 8;
  const int lin1 = lin0 + 512;
  const int am0 = lin0 >> 5, ac0 = lin0 & 31;
  const int am1 = lin1 >> 5, ac1 = lin1 & 31;

  const ushort* pa0 = A + (size_t)(m0 + am0) * As + ac0;
  const ushort* pa1 = A + (size_t)(m0 + am1) * As + ac1;
  const ushort* pb0 = W + (size_t)(n0 + am0) * Ws + ac0;
  const ushort* pb1 = W + (size_t)(n0 + am1) * Ws + ac1;
  ushort* la0 = &la[wv * 1024];
  ushort* la1 = &la[wv * 1024 + 512];
  ushort* lb0 = &lb[wv * 1024];
  ushort* lb1 = &lb[wv * 1024 + 512];

  f32x4 acc[4][4];
#pragma unroll
  for (int i = 0; i < 4; ++i)
#pragma unroll
    for (int j = 0; j < 4; ++j) acc[i][j] = (f32x4)(0.f);

  const int KT = K >> 5;
  for (int kt = 0; kt < KT; ++kt) {
    const int kb = kt << 5;
    GLOAD16(pa0 + kb, la0);
    GLOAD16(pa1 + kb, la1);
    GLOAD16(pb0 + kb, lb0);
    GLOAD16(pb1 + kb, lb1);
    __syncthreads();
    bf16x8 av[4], bv[4];
#pragma unroll
    for (int i = 0; i < 4; ++i)
      av[i] = *(const bf16x8*)&la[(wm + i * 16 + tr) * 32 + tq * 8];
#pragma unroll
    for (int j = 0; j < 4; ++j)
      bv[j] = *(const bf16x8*)&lb[(wn + j * 16 + tr) * 32 + tq * 8];
#pragma unroll
    for (int i = 0; i < 4; ++i)
#pragma unroll
      for (int j = 0; j < 4; ++j)
        acc[i][j] =
            __builtin_amdgcn_mfma_f32_16x16x32_bf16(av[i], bv[j], acc[i][j], 0, 0, 0);
    __syncthreads();
  }

#pragma unroll
  for (int j = 0; j < 4; ++j) {
    const int gn = n0 + wn + j * 16 + tr;
    float bj = 0.f;
    if (MODE != 2) bj = bias[gn];
    float scl = 1.f;
    if (MODE == 4) scl = (gn < 512) ? 0.18033688011112042f : 1.f;
#pragma unroll
    for (int i = 0; i < 4; ++i) {
      const int gmb = m0 + wm + i * 16 + tq * 4;
#pragma unroll
      for (int r = 0; r < 4; ++r) {
        const size_t idx = (size_t)(gmb + r) * Cs + gn;
        float v = acc[i][j][r] + bj;
        if (MODE == 1) v = fmaxf(v, 0.f);
        if (MODE == 4) v *= scl;
        if (MODE == 3)
          ((float*)Cv)[idx] = v;
        else if (MODE == 2) {
          ushort* C = (ushort*)Cv;
          C[idx] = f2b(b2f(C[idx]) + acc[i][j][r]);
        } else
          ((ushort*)Cv)[idx] = f2b(v);
      }
    }
  }
}

// --- batched MFMA GEMM, W fp32 converted during staging (Round-4-verified) --
// C_z = A_z[.,K](As) . W_z(Ws)[N][K]^T + bias_z ; z = blockIdx.z
__global__ __launch_bounds__(256) void gemm_btf(
    const ushort* __restrict__ A0, long zA, const float* __restrict__ W0,
    long zW, const float* __restrict__ bias0, long zb, ushort* __restrict__ C0,
    long zC, int N, int K, int As, int Ws, int Cs) {
  const int zz = blockIdx.z;
  const ushort* A = A0 + zA * zz;
  const float* W = W0 + zW * zz;
  const float* bias = bias0 + zb * zz;
  ushort* C = C0 + zC * zz;

  __shared__ ushort la[128 * 32];
  __shared__ ushort lb[128 * 32];
  const int tid = threadIdx.x;
  const int wv = tid >> 6, lane = tid & 63;
  const int m0 = blockIdx.y << 7, n0 = blockIdx.x << 7;
  const int wm = (wv >> 1) << 6, wn = (wv & 1) << 6;
  const int tr = lane & 15, tq = lane >> 4;

  const int lin0 = wv * 1024 + lane * 8;
  const int lin1 = lin0 + 512;
  const int am0 = lin0 >> 5, ac0 = lin0 & 31;
  const int am1 = lin1 >> 5, ac1 = lin1 & 31;

  const ushort* pa0 = A + (size_t)(m0 + am0) * As + ac0;
  const ushort* pa1 = A + (size_t)(m0 + am1) * As + ac1;
  const float* pb0 = W + (size_t)(n0 + am0) * Ws + ac0;
  const float* pb1 = W + (size_t)(n0 + am1) * Ws + ac1;

  f32x4 acc[4][4];
#pragma unroll
  for (int i = 0; i < 4; ++i)
#pragma unroll
    for (int j = 0; j < 4; ++j) acc[i][j] = (f32x4)(0.f);

  const int KT = K >> 5;
  for (int kt = 0; kt < KT; ++kt) {
    const int kb = kt << 5;
    uint4 ra0 = *(const uint4*)(pa0 + kb);
    uint4 ra1 = *(const uint4*)(pa1 + kb);
    float4 f00 = *(const float4*)(pb0 + kb);
    float4 f01 = *(const float4*)(pb0 + kb + 4);
    float4 f10 = *(const float4*)(pb1 + kb);
    float4 f11 = *(const float4*)(pb1 + kb + 4);
    uint4 rb0 = make_uint4(pack2(f00.x, f00.y), pack2(f00.z, f00.w),
                           pack2(f01.x, f01.y), pack2(f01.z, f01.w));
    uint4 rb1 = make_uint4(pack2(f10.x, f10.y), pack2(f10.z, f10.w),
                           pack2(f11.x, f11.y), pack2(f11.z, f11.w));
    __syncthreads();
    *(uint4*)&la[lin0] = ra0;
    *(uint4*)&la[lin1] = ra1;
    *(uint4*)&lb[lin0] = rb0;
    *(uint4*)&lb[lin1] = rb1;
    __syncthreads();
    bf16x8 av[4], bv[4];
#pragma unroll
    for (int i = 0; i < 4; ++i)
      av[i] = *(const bf16x8*)&la[(wm + i * 16 + tr) * 32 + tq * 8];
#pragma unroll
    for (int j = 0; j < 4; ++j)
      bv[j] = *(const bf16x8*)&lb[(wn + j * 16 + tr) * 32 + tq * 8];
#pragma unroll
    for (int i = 0; i < 4; ++i)
#pragma unroll
      for (int j = 0; j < 4; ++j)
        acc[i][j] =
            __builtin_amdgcn_mfma_f32_16x16x32_bf16(av[i], bv[j], acc[i][j], 0, 0, 0);
  }

#pragma unroll
  for (int j = 0; j < 4; ++j) {
    const int gn = n0 + wn + j * 16 + tr;
    const float bj = bias[gn];
#pragma unroll
    for (int i = 0; i < 4; ++i) {
      const int gmb = m0 + wm + i * 16 + tq * 4;
#pragma unroll
      for (int r = 0; r < 4; ++r)
        C[(size_t)(gmb + r) * Cs + gn] = f2b(acc[i][j][r] + bj);
    }
  }
}

// ---------------- MFMA causal attention v3 ----------------
// grid (2, H, B), 128 threads (2 waves). Wave g owns q-chunk qc=2*qp+g.
// K staged [key][d]; V staged TRANSPOSED [d][key] so PV B-frags are b128.
// Q pre-scaled by log2(e)/8 in QKV GEMM. In-place output over q-slice.
// P relay is per-wave LDS (in-order LDS pipe) -> no barrier between P and PV.
__global__ __launch_bounds__(128) void attn_mfma(ushort* __restrict__ qkv) {
  __shared__ ushort lk[64 * 72];      // K chunk  [key][64+8]
  __shared__ ushort lvT[64 * 72];     // V^T      [d][64+8]
  __shared__ ushort lp[2 * 64 * 72];  // per-wave P [qrow][64+8]
  const int qp = blockIdx.x, h = blockIdx.y, b = blockIdx.z;
  const int tid = threadIdx.x;
  const int g = tid >> 6, lane = tid & 63;
  const int tr = lane & 15, tq = lane >> 4;
  const int qc = qp * 2 + g;
  const int q0 = qc << 6;
  ushort* myp = &lp[g * 64 * 72];

  bf16x8 qf[4][2];
#pragma unroll
  for (int i = 0; i < 4; ++i)
#pragma unroll
    for (int s = 0; s < 2; ++s)
      qf[i][s] = *(const bf16x8*)(qkv +
                                  (size_t)(b * 256 + q0 + i * 16 + tr) * 1536 +
                                  h * 64 + s * 32 + tq * 8);

  f32x4 o[4][4];
  float pl[4][4];
#pragma unroll
  for (int i = 0; i < 4; ++i)
#pragma unroll
    for (int j = 0; j < 4; ++j) {
      o[i][j] = (f32x4)(0.f);
      pl[i][j] = 0.f;
    }

  const int key = tid >> 1, half = tid & 1;
  const int cmax = qp * 2 + 1;
  for (int c = 0; c <= cmax; ++c) {
    __syncthreads();  // protect prior chunk's lk/lvT reads
    const ushort* gk =
        qkv + (size_t)(b * 256 + c * 64 + key) * 1536 + 512 + h * 64 + half * 32;
#pragma unroll
    for (int u = 0; u < 4; ++u)
      *(uint4*)&lk[key * 72 + half * 32 + u * 8] = *(const uint4*)(gk + u * 8);
    ushort vloc[32];
#pragma unroll
    for (int u = 0; u < 4; ++u)
      *(uint4*)&vloc[u * 8] = *(const uint4*)(gk + 512 + u * 8);
#pragma unroll
    for (int dd = 0; dd < 32; ++dd)
      lvT[(half * 32 + dd) * 72 + key] = vloc[dd];
    __syncthreads();

    if (c <= qc) {
      // S = Q . K^T
      f32x4 Sv[4][4];
#pragma unroll
      for (int i = 0; i < 4; ++i)
#pragma unroll
        for (int j = 0; j < 4; ++j) Sv[i][j] = (f32x4)(0.f);
      bf16x8 kf[4][2];
#pragma unroll
      for (int j = 0; j < 4; ++j)
#pragma unroll
        for (int s = 0; s < 2; ++s)
          kf[j][s] = *(const bf16x8*)&lk[(j * 16 + tr) * 72 + s * 32 + tq * 8];
#pragma unroll
      for (int i = 0; i < 4; ++i)
#pragma unroll
        for (int j = 0; j < 4; ++j) {
          Sv[i][j] = __builtin_amdgcn_mfma_f32_16x16x32_bf16(qf[i][0], kf[j][0],
                                                             Sv[i][j], 0, 0, 0);
          Sv[i][j] = __builtin_amdgcn_mfma_f32_16x16x32_bf16(qf[i][1], kf[j][1],
                                                             Sv[i][j], 0, 0, 0);
        }
      // exp2 (Q pre-scaled) + causal mask + partial rowsums + P -> own LDS
      const bool diag = (c == qc);
#pragma unroll
      for (int i = 0; i < 4; ++i)
#pragma unroll
        for (int j = 0; j < 4; ++j)
#pragma unroll
          for (int r = 0; r < 4; ++r) {
            float e = exp2f(Sv[i][j][r]);
            if (diag && (j * 16 + tr) > (i * 16 + tq * 4 + r)) e = 0.f;
            pl[i][r] += e;
            myp[(i * 16 + tq * 4 + r) * 72 + j * 16 + tr] =
                (ushort)(__float_as_uint(e) >> 16);  // trunc: P in [0,1]
          }
      // O += P . V  (same-wave LDS RAW: in-order DS pipe, no barrier)
#pragma unroll
      for (int s = 0; s < 2; ++s) {
        bf16x8 vf[4], af[4];
#pragma unroll
        for (int jn = 0; jn < 4; ++jn)
          vf[jn] = *(const bf16x8*)&lvT[(jn * 16 + tr) * 72 + s * 32 + tq * 8];
#pragma unroll
        for (int im = 0; im < 4; ++im)
          af[im] = *(const bf16x8*)&myp[(im * 16 + tr) * 72 + s * 32 + tq * 8];
#pragma unroll
        for (int im = 0; im < 4; ++im)
#pragma unroll
          for (int jn = 0; jn < 4; ++jn)
            o[im][jn] = __builtin_amdgcn_mfma_f32_16x16x32_bf16(af[im], vf[jn],
                                                                o[im][jn], 0, 0, 0);
      }
    }
  }

#pragma unroll
  for (int i = 0; i < 4; ++i)
#pragma unroll
    for (int r = 0; r < 4; ++r) {
      float v = pl[i][r];
      v += __shfl_xor(v, 1, 64);
      v += __shfl_xor(v, 2, 64);
      v += __shfl_xor(v, 4, 64);
      v += __shfl_xor(v, 8, 64);
      pl[i][r] = 1.f / v;
    }

#pragma unroll
  for (int i = 0; i < 4; ++i)
#pragma unroll
    for (int j = 0; j < 4; ++j)
#pragma unroll
      for (int r = 0; r < 4; ++r)
        qkv[(size_t)(b * 256 + q0 + i * 16 + tq * 4 + r) * 1536 + h * 64 +
            j * 16 + tr] = f2b(o[i][j][r] * pl[i][r]);
}

// ---- fused LN1+LN2: x = LN2(LN1(x + d1) + cavec16[b]) ---------------------
__global__ __launch_bounds__(256) void ln12_kernel(
    ushort* __restrict__ x16, const uint* __restrict__ d1,
    const uint* __restrict__ cavec, const float* __restrict__ s1,
    const float* __restrict__ b1, const float* __restrict__ s2,
    const float* __restrict__ b2p) {
  const int r = blockIdx.x, t = threadIdx.x;
  const int lane = t & 63, wv = t >> 6;
  uint* xr = (uint*)x16 + (size_t)r * 256;
  uint xu = xr[t];
  uint du = d1[(size_t)r * 768 + t];
  float v0 = blo(xu) + blo(du), v1 = bhi(xu) + bhi(du);
  __shared__ float redA[4][2], redB[4][2];
  float sm = v0 + v1, sq = v0 * v0 + v1 * v1;
#pragma unroll
  for (int o = 32; o > 0; o >>= 1) {
    sm += __shfl_xor(sm, o, 64);
    sq += __shfl_xor(sq, o, 64);
  }
  if (lane == 0) {
    redA[wv][0] = sm;
    redA[wv][1] = sq;
  }
  __syncthreads();
  sm = redA[0][0] + redA[1][0] + redA[2][0] + redA[3][0];
  sq = redA[0][1] + redA[1][1] + redA[2][1] + redA[3][1];
  float mean = sm * (1.f / 512.f);
  float var = sq * (1.f / 512.f) - mean * mean;
  float rs = rsqrtf(var + 1e-5f);
  float2 sa = ((const float2*)s1)[t];
  float2 ba = ((const float2*)b1)[t];
  uint cu = cavec[(size_t)(r >> 8) * 256 + t];
  float w0 = (v0 - mean) * rs * sa.x + ba.x + blo(cu);
  float w1 = (v1 - mean) * rs * sa.y + ba.y + bhi(cu);
  sm = w0 + w1;
  sq = w0 * w0 + w1 * w1;
#pragma unroll
  for (int o = 32; o > 0; o >>= 1) {
    sm += __shfl_xor(sm, o, 64);
    sq += __shfl_xor(sq, o, 64);
  }
  if (lane == 0) {
    redB[wv][0] = sm;
    redB[wv][1] = sq;
  }
  __syncthreads();
  sm = redB[0][0] + redB[1][0] + redB[2][0] + redB[3][0];
  sq = redB[0][1] + redB[1][1] + redB[2][1] + redB[3][1];
  mean = sm * (1.f / 512.f);
  var = sq * (1.f / 512.f) - mean * mean;
  rs = rsqrtf(var + 1e-5f);
  float2 sb = ((const float2*)s2)[t];
  float2 bb = ((const float2*)b2p)[t];
  float y0 = (w0 - mean) * rs * sb.x + bb.x;
  float y1 = (w1 - mean) * rs * sb.y + bb.y;
  xr[t] = pack2(y0, y1);
}

// -------- LayerNorm: x16 = bf16(LN(x16 + delta) * sc + bi), in place --------
__global__ __launch_bounds__(256) void ln_kernel(
    ushort* __restrict__ x16, const uint* __restrict__ delta, int DsU,
    const float* __restrict__ sc, const float* __restrict__ bi) {
  const int r = blockIdx.x, t = threadIdx.x;
  const int lane = t & 63, wv = t >> 6;
  uint* xr = (uint*)x16 + (size_t)r * 256;
  uint xu = xr[t];
  uint du = delta[(size_t)r * DsU + t];
  float v0 = blo(xu) + blo(du), v1 = bhi(xu) + bhi(du);
  float sm = v0 + v1, sq = v0 * v0 + v1 * v1;
#pragma unroll
  for (int o = 32; o > 0; o >>= 1) {
    sm += __shfl_xor(sm, o, 64);
    sq += __shfl_xor(sq, o, 64);
  }
  __shared__ float red[4][2];
  if (lane == 0) {
    red[wv][0] = sm;
    red[wv][1] = sq;
  }
  __syncthreads();
  sm = red[0][0] + red[1][0] + red[2][0] + red[3][0];
  sq = red[0][1] + red[1][1] + red[2][1] + red[3][1];
  float mean = sm * (1.f / 512.f);
  float var = sq * (1.f / 512.f) - mean * mean;
  float rs = rsqrtf(var + 1e-5f);
  float2 s2 = ((const float2*)sc)[t];
  float2 b2 = ((const float2*)bi)[t];
  float y0 = (v0 - mean) * rs * s2.x + b2.x;
  float y1 = (v1 - mean) * rs * s2.y + b2.y;
  xr[t] = pack2(y0, y1);
}

extern "C" void kernel_launch(void* const* d_in, const int* in_sizes, int n_in,
                              void* d_out, int out_size, void* d_ws,
                              size_t ws_size, hipStream_t stream) {
  (void)in_sizes; (void)n_in; (void)out_size; (void)ws_size;
  const float* z = (const float*)d_in[0];
  const int* tgt = (const int*)d_in[1];
  const float* emb = (const float*)d_in[2];
  const float* pos = (const float*)d_in[3];
  const float* projw = (const float*)d_in[4];
  const float* projb = (const float*)d_in[5];
  const float* saw = (const float*)d_in[6];
  const float* sab = (const float*)d_in[7];
  const float* saow = (const float*)d_in[8];
  const float* saob = (const float*)d_in[9];
  const float* caw = (const float*)d_in[10];
  const float* cab = (const float*)d_in[11];
  const float* caow = (const float*)d_in[12];
  const float* caob = (const float*)d_in[13];
  const float* ln1s = (const float*)d_in[14];
  const float* ln1b = (const float*)d_in[15];
  const float* ln2s = (const float*)d_in[16];
  const float* ln2b = (const float*)d_in[17];
  const float* ln3s = (const float*)d_in[18];
  const float* ln3b = (const float*)d_in[19];
  const float* ff1w = (const float*)d_in[20];
  const float* ff1b = (const float*)d_in[21];
  const float* ff2w = (const float*)d_in[22];
  const float* ff2b = (const float*)d_in[23];
  const float* fcw = (const float*)d_in[24];
  const float* fcb = (const float*)d_in[25];

  // workspace carve — TOTAL ~103 MiB:
  // [0,16M)    x16 bf16 residual
  // [16M,64M)  qkv 48M (attn in-place; out-proj delta in dead k-slice);
  //            FF phase: hbuf 32M + fdel 16M
  // [64M,66M)  bf16 smalls: z16(128x512) memv16(128x512) cav16(6x128x512)
  //            cavec16(6x128x512) — rows 64..127 are junk (M padded to 128)
  // [66M,~103M) bf16 weights (converted once per launch)
  char* w8 = (char*)d_ws;
  ushort* x16 = (ushort*)w8;
  ushort* qkv = (ushort*)(w8 + (16u << 20));
  ushort* hbuf = qkv;
  ushort* fdel = (ushort*)(w8 + (48u << 20));
  ushort* z16 = (ushort*)(w8 + (64u << 20));
  ushort* memv16 = z16 + 128 * 512;
  ushort* cav16 = memv16 + 128 * 512;
  ushort* cavec16 = cav16 + (size_t)L_ * 128 * 512;
  ushort* wsaw = (ushort*)(w8 + (66u << 20));
  ushort* wsaow = wsaw + (size_t)L_ * 1536 * 512;
  ushort* wff1 = wsaow + (size_t)L_ * 512 * 512;
  ushort* wff2 = wff1 + (size_t)L_ * 2048 * 512;
  ushort* wfcw = wff2 + (size_t)L_ * 512 * 2048;

  // one-time weight conversions (fp32 -> bf16)
  conv_kernel<<<(L_ * 1536 * 512) / 512, 256, 0, stream>>>(saw, wsaw);
  conv_kernel<<<(L_ * 512 * 512) / 512, 256, 0, stream>>>(saow, wsaow);
  conv_kernel<<<(L_ * 2048 * 512) / 512, 256, 0, stream>>>(ff1w, wff1);
  conv_kernel<<<(L_ * 512 * 2048) / 512, 256, 0, stream>>>(ff2w, wff2);
  conv_kernel<<<(V_ * 512) / 512, 256, 0, stream>>>(fcw, wfcw);
  conv_kernel<<<(B_ * 512) / 512, 256, 0, stream>>>(z, z16);

  embed_kernel<<<16384, 256, 0, stream>>>(tgt, emb, pos, x16);

  // collapsed cross-attention (kv len 1) via padded-M MFMA, all batched:
  // memv16 = z16 . projw^T + projb
  gemm_btf<<<dim3(4, 1, 1), 256, 0, stream>>>(z16, 0, projw, 0, projb, 0,
                                              memv16, 0, 512, 512, 512, 512, 512);
  // cav16[l] = memv16 . Wv_l^T + bv_l
  gemm_btf<<<dim3(4, 1, L_), 256, 0, stream>>>(
      memv16, 0, caw + 1024 * 512, (long)1536 * 512, cab + 1024, 1536, cav16,
      (long)128 * 512, 512, 512, 512, 512, 512);
  // cavec16[l] = cav16[l] . Wo_l^T + bo_l
  gemm_btf<<<dim3(4, 1, L_), 256, 0, stream>>>(
      cav16, (long)128 * 512, caow, (long)512 * 512, caob, 512, cavec16,
      (long)128 * 512, 512, 512, 512, 512, 512);

  for (int i = 0; i < L_; ++i) {
    // QKV (+ Q pre-scale): qkv = x16 . sa_w^T + sa_b
    gemm_rs<4><<<dim3(12, 128), 256, 0, stream>>>(
        x16, wsaw + (size_t)i * 1536 * 512, sab + i * 1536, qkv, 1536, 512, 512,
        512, 1536);
    attn_mfma<<<dim3(2, H_, B_), 128, 0, stream>>>(qkv);
    // out-proj -> dead k-slice
    gemm_rs<0><<<dim3(4, 128), 256, 0, stream>>>(
        qkv, wsaow + (size_t)i * 512 * 512, saob + i * 512, qkv + 512, 512, 512,
        1536, 512, 1536);
    // fused LN1 + cross-attn add + LN2
    ln12_kernel<<<16384, 256, 0, stream>>>(
        x16, (const uint*)(qkv + 512), (const uint*)(cavec16 + (size_t)i * 128 * 512),
        ln1s + i * 512, ln1b + i * 512, ln2s + i * 512, ln2b + i * 512);
    // FFN split into two DFF=1024 chunks
    gemm_rs<1><<<dim3(8, 128), 256, 0, stream>>>(
        x16, wff1 + (size_t)i * 2048 * 512, ff1b + i * 2048, hbuf, 1024, 512,
        512, 512, 1024);
    gemm_rs<0><<<dim3(4, 128), 256, 0, stream>>>(
        hbuf, wff2 + (size_t)i * 512 * 2048, ff2b + i * 512, fdel, 512, 1024,
        1024, 2048, 512);
    gemm_rs<1><<<dim3(8, 128), 256, 0, stream>>>(
        x16, wff1 + ((size_t)i * 2048 + 1024) * 512, ff1b + i * 2048 + 1024,
        hbuf, 1024, 512, 512, 512, 1024);
    gemm_rs<2><<<dim3(4, 128), 256, 0, stream>>>(
        hbuf, wff2 + (size_t)i * 512 * 2048 + 1024, (const float*)0, fdel, 512,
        1024, 1024, 2048, 512);
    ln_kernel<<<16384, 256, 0, stream>>>(x16, (const uint*)fdel, 256,
                                         ln3s + i * 512, ln3b + i * 512);
  }
  gemm_bt<3><<<dim3(1, 128), 256, 0, stream>>>(x16, wfcw, fcb, d_out, 128, 512,
                                               512, 512, 128);
}

// Round 7
// 1611.469 us; speedup vs baseline: 1.1810x; 1.0002x over previous
//
#include <hip/hip_runtime.h>

typedef unsigned int uint;
typedef unsigned short ushort;

typedef __attribute__((ext_vector_type(8))) __bf16 bf16x8;
typedef __attribute__((ext_vector_type(4))) float f32x4;

#define B_ 64
#define S_ 256
#define D_ 512
#define H_ 8
#define DFF_ 2048
#define V_ 128
#define L_ 6
#define BS_ (B_ * S_)

__device__ __forceinline__ float blo(uint u) { return __uint_as_float(u << 16); }
__device__ __forceinline__ float bhi(uint u) { return __uint_as_float(u & 0xffff0000u); }
__device__ __forceinline__ float b2f(ushort u) { return __uint_as_float(((uint)u) << 16); }
__device__ __forceinline__ ushort f2b(float f) {
  uint u = __float_as_uint(f);
  return (ushort)((u + 0x7fffu + ((u >> 16) & 1u)) >> 16);  // RTNE
}
__device__ __forceinline__ uint pack2(float a, float b) {
  return (uint)f2b(a) | ((uint)f2b(b) << 16);
}

#define GLOAD16(gp, lp)                                                        \
  __builtin_amdgcn_global_load_lds(                                            \
      (const __attribute__((address_space(1))) void*)(gp),                     \
      (__attribute__((address_space(3))) void*)(lp), 16, 0, 0)

// -------- fp32 -> bf16 bulk conversion (one-time per launch) ---------------
__global__ __launch_bounds__(256) void conv_kernel(const float* __restrict__ src,
                                                   ushort* __restrict__ dst) {
  size_t p = (size_t)blockIdx.x * 256 + threadIdx.x;
  float2 v = ((const float2*)src)[p];
  ((uint*)dst)[p] = pack2(v.x, v.y);
}

// -------- embedding: x16 = bf16(emb[tgt] + pos); emb/pos fp32 ---------------
__global__ __launch_bounds__(256) void embed_kernel(
    const int* __restrict__ tgt, const float* __restrict__ emb,
    const float* __restrict__ pos, ushort* __restrict__ x16) {
  int p = blockIdx.x * 256 + threadIdx.x;
  int row = p >> 8;
  int d2 = p & 255;
  int s = row & (S_ - 1);
  int tok = tgt[row];
  float2 e = ((const float2*)emb)[tok * 256 + d2];
  float2 pp = ((const float2*)pos)[s * 256 + d2];
  ((uint*)x16)[p] = pack2(e.x + pp.x, e.y + pp.y);
}

// fragment-read + operand-SWAPPED MFMA for one BK=64 tile.
// Swap (bv first) => acc[i][j][r] holds C[m = wm+i*16+tr][n = wn+j*16+tq*4+r]
// i.e. lane owns 4 CONSECUTIVE n at fixed m -> coalescible epilogue.
__device__ __forceinline__ void compute_tile(const ushort* base, int wm, int wn,
                                             int tr, int tq,
                                             f32x4 (&acc)[4][4]) {
  const ushort* sA = base;
  const ushort* sB = base + 8192;
  bf16x8 av[2][4], bv[2][4];
#pragma unroll
  for (int s = 0; s < 2; ++s) {
#pragma unroll
    for (int i = 0; i < 4; ++i)
      av[s][i] = *(const bf16x8*)&sA[s * 4096 + (wm + i * 16 + tr) * 32 + tq * 8];
#pragma unroll
    for (int j = 0; j < 4; ++j)
      bv[s][j] = *(const bf16x8*)&sB[s * 4096 + (wn + j * 16 + tr) * 32 + tq * 8];
  }
#pragma unroll
  for (int s = 0; s < 2; ++s)
#pragma unroll
    for (int i = 0; i < 4; ++i)
#pragma unroll
      for (int j = 0; j < 4; ++j)
        acc[i][j] = __builtin_amdgcn_mfma_f32_16x16x32_bf16(bv[s][j], av[s][i],
                                                            acc[i][j], 0, 0, 0);
}

// === 3-stage register-staged double-buffered BK=64 MFMA GEMM (T14) =========
// C = A[.,K](As) . W_bf16(Ws)[N][K]^T + bias. 128x128 tile, 4 waves.
// MODE 0: bf16(acc+bias)  1: relu  2: bf16 C+=acc  4: Q-prescale (cols<512)
// Pipeline (plain HIP; compiler emits COUNTED vmcnt for reg loads):
//   iter t: issue loads(tile t+2)->regset X | MFMA(buf d) |
//           ds_write regset Y (tile t+1, issued at iter t-1 => latency covered
//           by a full iteration + this iteration's MFMA) -> buf d^1 | barrier
// Two named reg sets (rule #20: no runtime-indexed arrays), loop unrolled x2.
// Epilogue: operand-swapped acc -> ds_write_b64 into [128][136] LDS, then
// fully-coalesced uint4 readback + global dwordx4 stores (pattern verified
// correct in round-1 gemm256). LDS 64KB single array, reused for epilogue.
// T1 bijective XCD swizzle (round-3 verified FETCH 69->20MB).
// Requires K%128==0 (KT even), M%128==0, N%128==0, nwg%8==0.
template <int MODE>
__global__ __launch_bounds__(256) void gemm_rs(
    const ushort* __restrict__ A, const ushort* __restrict__ W,
    const float* __restrict__ bias, void* __restrict__ Cv, int N, int K,
    int As, int Ws, int Cs) {
  __shared__ ushort lsh[32768];  // main: [2 buf][A 8192 | B 8192]; epi: [128][136]
  const int tid = threadIdx.x;
  const int wv = tid >> 6, lane = tid & 63;

  // bijective XCD-aware block swizzle (T1)
  const int nwg = gridDim.x * gridDim.y;
  int lid = blockIdx.x + gridDim.x * blockIdx.y;
  lid = (lid & 7) * (nwg >> 3) + (lid >> 3);
  const int bx = lid % gridDim.x;
  const int by = lid / gridDim.x;
  const int m0 = by << 7, n0 = bx << 7;

  const int wm = (wv >> 1) << 6, wn = (wv & 1) << 6;
  const int tr = lane & 15, tq = lane >> 4;

  // staging map: thread covers 16B at lin0 and lin0+512 within each 4096-
  // ushort k-sub-tile (linear, coalesced, 2-way bank = free).
  const int lin0 = wv * 1024 + lane * 8;
  const int am0 = lin0 >> 5, ac0 = lin0 & 31;
  const int lin1 = lin0 + 512;
  const int am1 = lin1 >> 5, ac1 = lin1 & 31;

  const ushort* pa0 = A + (size_t)(m0 + am0) * As + ac0;
  const ushort* pa1 = A + (size_t)(m0 + am1) * As + ac1;
  const ushort* pb0 = W + (size_t)(n0 + am0) * Ws + ac0;
  const ushort* pb1 = W + (size_t)(n0 + am1) * Ws + ac1;

  f32x4 acc[4][4];
#pragma unroll
  for (int i = 0; i < 4; ++i)
#pragma unroll
    for (int j = 0; j < 4; ++j) acc[i][j] = (f32x4)(0.f);

  const int KT = K >> 6;  // BK = 64; KT even (K=512 or 1024)

  uint4 sa0, sa1, sa2, sa3, sb0, sb1, sb2, sb3;  // reg set S
  uint4 ta0, ta1, ta2, ta3, tb0, tb1, tb2, tb3;  // reg set T

#define LOADS(t)                                                               \
  do {                                                                         \
    const int kb_ = (t) << 6;                                                  \
    sa0 = *(const uint4*)(pa0 + kb_);                                          \
    sa1 = *(const uint4*)(pa1 + kb_);                                          \
    sa2 = *(const uint4*)(pa0 + kb_ + 32);                                     \
    sa3 = *(const uint4*)(pa1 + kb_ + 32);                                     \
    sb0 = *(const uint4*)(pb0 + kb_);                                          \
    sb1 = *(const uint4*)(pb1 + kb_);                                          \
    sb2 = *(const uint4*)(pb0 + kb_ + 32);                                     \
    sb3 = *(const uint4*)(pb1 + kb_ + 32);                                     \
  } while (0)
#define LOADT(t)                                                               \
  do {                                                                         \
    const int kb_ = (t) << 6;                                                  \
    ta0 = *(const uint4*)(pa0 + kb_);                                          \
    ta1 = *(const uint4*)(pa1 + kb_);                                          \
    ta2 = *(const uint4*)(pa0 + kb_ + 32);                                     \
    ta3 = *(const uint4*)(pa1 + kb_ + 32);                                     \
    tb0 = *(const uint4*)(pb0 + kb_);                                          \
    tb1 = *(const uint4*)(pb1 + kb_);                                          \
    tb2 = *(const uint4*)(pb0 + kb_ + 32);                                     \
    tb3 = *(const uint4*)(pb1 + kb_ + 32);                                     \
  } while (0)
#define WRITS(d)                                                               \
  do {                                                                         \
    ushort* b_ = lsh + (d) * 16384;                                            \
    *(uint4*)&b_[lin0] = sa0;                                                  \
    *(uint4*)&b_[lin1] = sa1;                                                  \
    *(uint4*)&b_[4096 + lin0] = sa2;                                           \
    *(uint4*)&b_[4096 + lin1] = sa3;                                           \
    *(uint4*)&b_[8192 + lin0] = sb0;                                           \
    *(uint4*)&b_[8192 + lin1] = sb1;                                           \
    *(uint4*)&b_[12288 + lin0] = sb2;                                          \
    *(uint4*)&b_[12288 + lin1] = sb3;                                          \
  } while (0)
#define WRITT(d)                                                               \
  do {                                                                         \
    ushort* b_ = lsh + (d) * 16384;                                            \
    *(uint4*)&b_[lin0] = ta0;                                                  \
    *(uint4*)&b_[lin1] = ta1;                                                  \
    *(uint4*)&b_[4096 + lin0] = ta2;                                           \
    *(uint4*)&b_[4096 + lin1] = ta3;                                           \
    *(uint4*)&b_[8192 + lin0] = tb0;                                           \
    *(uint4*)&b_[8192 + lin1] = tb1;                                           \
    *(uint4*)&b_[12288 + lin0] = tb2;                                          \
    *(uint4*)&b_[12288 + lin1] = tb3;                                          \
  } while (0)

  // prologue: set S <- tile0, set T <- tile1; write tile0 (vmcnt counts only
  // S's 8 loads -> T stays in flight); barrier.
  LOADS(0);
  LOADT(1);
  WRITS(0);
  __syncthreads();

  for (int t = 0; t < KT; t += 2) {
    // ---- even iter: buf0 = tile t
    if (t + 2 < KT) LOADS(t + 2);           // S <- tile t+2 (async)
    compute_tile(lsh, wm, wn, tr, tq, acc); // MFMA on buf0
    if (t + 1 < KT) WRITT(1);               // tile t+1 (issued >=1 iter ago)
    __syncthreads();
    // ---- odd iter: buf1 = tile t+1
    if (t + 3 < KT) LOADT(t + 3);           // T <- tile t+3 (async)
    compute_tile(lsh + 16384, wm, wn, tr, tq, acc);
    if (t + 2 < KT) WRITS(0);               // tile t+2
    __syncthreads();
  }
#undef LOADS
#undef LOADT
#undef WRITS
#undef WRITT

  // ---- epilogue: acc (lane = 4 consecutive n at fixed m) -> LDS -> global.
  // Final loop barrier already fenced all frag reads; safe to reuse lsh.
#pragma unroll
  for (int i = 0; i < 4; ++i)
#pragma unroll
    for (int j = 0; j < 4; ++j) {
      const int gn4 = n0 + wn + j * 16 + tq * 4;
      float b0 = 0.f, b1 = 0.f, b2 = 0.f, b3 = 0.f;
      if (MODE != 2) {
        float4 bb = ((const float4*)bias)[gn4 >> 2];
        b0 = bb.x; b1 = bb.y; b2 = bb.z; b3 = bb.w;
      }
      float v0 = acc[i][j][0] + b0, v1 = acc[i][j][1] + b1,
            v2 = acc[i][j][2] + b2, v3 = acc[i][j][3] + b3;
      if (MODE == 1) {
        v0 = fmaxf(v0, 0.f); v1 = fmaxf(v1, 0.f);
        v2 = fmaxf(v2, 0.f); v3 = fmaxf(v3, 0.f);
      }
      if (MODE == 4) {
        const float scl = (gn4 < 512) ? 0.18033688011112042f : 1.f;
        v0 *= scl; v1 *= scl; v2 *= scl; v3 *= scl;
      }
      uint2 pk;
      pk.x = pack2(v0, v1);
      pk.y = pack2(v2, v3);
      *(uint2*)&lsh[(wm + i * 16 + tr) * 136 + wn + j * 16 + tq * 4] = pk;
    }
  __syncthreads();
#pragma unroll
  for (int u = 0; u < 8; ++u) {
    const int f = u * 256 + tid;
    const int row = f >> 4, sl = f & 15;
    uint4 val = *(const uint4*)&lsh[row * 136 + sl * 8];
    ushort* gp = (ushort*)Cv + (size_t)(m0 + row) * Cs + n0 + sl * 8;
    if (MODE == 2) {
      uint4 c = *(const uint4*)gp;
      val.x = pack2(blo(val.x) + blo(c.x), bhi(val.x) + bhi(c.x));
      val.y = pack2(blo(val.y) + blo(c.y), bhi(val.y) + bhi(c.y));
      val.z = pack2(blo(val.z) + blo(c.z), bhi(val.z) + bhi(c.z));
      val.w = pack2(blo(val.w) + blo(c.w), bhi(val.w) + bhi(c.w));
    }
    *(uint4*)gp = val;
  }
}

// --- MFMA GEMM (m97 structure + T1 swizzle), kept for final fc -------------
// MODE 3: fp32 acc+bias
template <int MODE>
__global__ __launch_bounds__(256) void gemm_bt(
    const ushort* __restrict__ A, const ushort* __restrict__ W,
    const float* __restrict__ bias, void* __restrict__ Cv, int N, int K,
    int As, int Ws, int Cs) {
  __shared__ ushort la[128 * 32];
  __shared__ ushort lb[128 * 32];
  const int tid = threadIdx.x;
  const int wv = tid >> 6, lane = tid & 63;

  const int nwg = gridDim.x * gridDim.y;
  int lid = blockIdx.x + gridDim.x * blockIdx.y;
  lid = (lid & 7) * (nwg >> 3) + (lid >> 3);
  const int bx = lid % gridDim.x;
  const int by = lid / gridDim.x;
  const int m0 = by << 7, n0 = bx << 7;

  const int wm = (wv >> 1) << 6, wn = (wv & 1) << 6;
  const int tr = lane & 15, tq = lane >> 4;

  const int lin0 = wv * 1024 + lane * 8;
  const int lin1 = lin0 + 512;
  const int am0 = lin0 >> 5, ac0 = lin0 & 31;
  const int am1 = lin1 >> 5, ac1 = lin1 & 31;

  const ushort* pa0 = A + (size_t)(m0 + am0) * As + ac0;
  const ushort* pa1 = A + (size_t)(m0 + am1) * As + ac1;
  const ushort* pb0 = W + (size_t)(n0 + am0) * Ws + ac0;
  const ushort* pb1 = W + (size_t)(n0 + am1) * Ws + ac1;
  ushort* la0 = &la[wv * 1024];
  ushort* la1 = &la[wv * 1024 + 512];
  ushort* lb0 = &lb[wv * 1024];
  ushort* lb1 = &lb[wv * 1024 + 512];

  f32x4 acc[4][4];
#pragma unroll
  for (int i = 0; i < 4; ++i)
#pragma unroll
    for (int j = 0; j < 4; ++j) acc[i][j] = (f32x4)(0.f);

  const int KT = K >> 5;
  for (int kt = 0; kt < KT; ++kt) {
    const int kb = kt << 5;
    GLOAD16(pa0 + kb, la0);
    GLOAD16(pa1 + kb, la1);
    GLOAD16(pb0 + kb, lb0);
    GLOAD16(pb1 + kb, lb1);
    __syncthreads();
    bf16x8 av[4], bv[4];
#pragma unroll
    for (int i = 0; i < 4; ++i)
      av[i] = *(const bf16x8*)&la[(wm + i * 16 + tr) * 32 + tq * 8];
#pragma unroll
    for (int j = 0; j < 4; ++j)
      bv[j] = *(const bf16x8*)&lb[(wn + j * 16 + tr) * 32 + tq * 8];
#pragma unroll
    for (int i = 0; i < 4; ++i)
#pragma unroll
      for (int j = 0; j < 4; ++j)
        acc[i][j] =
            __builtin_amdgcn_mfma_f32_16x16x32_bf16(av[i], bv[j], acc[i][j], 0, 0, 0);
    __syncthreads();
  }

#pragma unroll
  for (int j = 0; j < 4; ++j) {
    const int gn = n0 + wn + j * 16 + tr;
    float bj = 0.f;
    if (MODE != 2) bj = bias[gn];
    float scl = 1.f;
    if (MODE == 4) scl = (gn < 512) ? 0.18033688011112042f : 1.f;
#pragma unroll
    for (int i = 0; i < 4; ++i) {
      const int gmb = m0 + wm + i * 16 + tq * 4;
#pragma unroll
      for (int r = 0; r < 4; ++r) {
        const size_t idx = (size_t)(gmb + r) * Cs + gn;
        float v = acc[i][j][r] + bj;
        if (MODE == 1) v = fmaxf(v, 0.f);
        if (MODE == 4) v *= scl;
        if (MODE == 3)
          ((float*)Cv)[idx] = v;
        else if (MODE == 2) {
          ushort* C = (ushort*)Cv;
          C[idx] = f2b(b2f(C[idx]) + acc[i][j][r]);
        } else
          ((ushort*)Cv)[idx] = f2b(v);
      }
    }
  }
}

// --- batched MFMA GEMM, W fp32 converted during staging (Round-4-verified) --
// C_z = A_z[.,K](As) . W_z(Ws)[N][K]^T + bias_z ; z = blockIdx.z
__global__ __launch_bounds__(256) void gemm_btf(
    const ushort* __restrict__ A0, long zA, const float* __restrict__ W0,
    long zW, const float* __restrict__ bias0, long zb, ushort* __restrict__ C0,
    long zC, int N, int K, int As, int Ws, int Cs) {
  const int zz = blockIdx.z;
  const ushort* A = A0 + zA * zz;
  const float* W = W0 + zW * zz;
  const float* bias = bias0 + zb * zz;
  ushort* C = C0 + zC * zz;

  __shared__ ushort la[128 * 32];
  __shared__ ushort lb[128 * 32];
  const int tid = threadIdx.x;
  const int wv = tid >> 6, lane = tid & 63;
  const int m0 = blockIdx.y << 7, n0 = blockIdx.x << 7;
  const int wm = (wv >> 1) << 6, wn = (wv & 1) << 6;
  const int tr = lane & 15, tq = lane >> 4;

  const int lin0 = wv * 1024 + lane * 8;
  const int lin1 = lin0 + 512;
  const int am0 = lin0 >> 5, ac0 = lin0 & 31;
  const int am1 = lin1 >> 5, ac1 = lin1 & 31;

  const ushort* pa0 = A + (size_t)(m0 + am0) * As + ac0;
  const ushort* pa1 = A + (size_t)(m0 + am1) * As + ac1;
  const float* pb0 = W + (size_t)(n0 + am0) * Ws + ac0;
  const float* pb1 = W + (size_t)(n0 + am1) * Ws + ac1;

  f32x4 acc[4][4];
#pragma unroll
  for (int i = 0; i < 4; ++i)
#pragma unroll
    for (int j = 0; j < 4; ++j) acc[i][j] = (f32x4)(0.f);

  const int KT = K >> 5;
  for (int kt = 0; kt < KT; ++kt) {
    const int kb = kt << 5;
    uint4 ra0 = *(const uint4*)(pa0 + kb);
    uint4 ra1 = *(const uint4*)(pa1 + kb);
    float4 f00 = *(const float4*)(pb0 + kb);
    float4 f01 = *(const float4*)(pb0 + kb + 4);
    float4 f10 = *(const float4*)(pb1 + kb);
    float4 f11 = *(const float4*)(pb1 + kb + 4);
    uint4 rb0 = make_uint4(pack2(f00.x, f00.y), pack2(f00.z, f00.w),
                           pack2(f01.x, f01.y), pack2(f01.z, f01.w));
    uint4 rb1 = make_uint4(pack2(f10.x, f10.y), pack2(f10.z, f10.w),
                           pack2(f11.x, f11.y), pack2(f11.z, f11.w));
    __syncthreads();
    *(uint4*)&la[lin0] = ra0;
    *(uint4*)&la[lin1] = ra1;
    *(uint4*)&lb[lin0] = rb0;
    *(uint4*)&lb[lin1] = rb1;
    __syncthreads();
    bf16x8 av[4], bv[4];
#pragma unroll
    for (int i = 0; i < 4; ++i)
      av[i] = *(const bf16x8*)&la[(wm + i * 16 + tr) * 32 + tq * 8];
#pragma unroll
    for (int j = 0; j < 4; ++j)
      bv[j] = *(const bf16x8*)&lb[(wn + j * 16 + tr) * 32 + tq * 8];
#pragma unroll
    for (int i = 0; i < 4; ++i)
#pragma unroll
      for (int j = 0; j < 4; ++j)
        acc[i][j] =
            __builtin_amdgcn_mfma_f32_16x16x32_bf16(av[i], bv[j], acc[i][j], 0, 0, 0);
  }

#pragma unroll
  for (int j = 0; j < 4; ++j) {
    const int gn = n0 + wn + j * 16 + tr;
    const float bj = bias[gn];
#pragma unroll
    for (int i = 0; i < 4; ++i) {
      const int gmb = m0 + wm + i * 16 + tq * 4;
#pragma unroll
      for (int r = 0; r < 4; ++r)
        C[(size_t)(gmb + r) * Cs + gn] = f2b(acc[i][j][r] + bj);
    }
  }
}

// ---------------- MFMA causal attention v3 ----------------
// grid (2, H, B), 128 threads (2 waves). Wave g owns q-chunk qc=2*qp+g.
// K staged [key][d]; V staged TRANSPOSED [d][key] so PV B-frags are b128.
// Q pre-scaled by log2(e)/8 in QKV GEMM. In-place output over q-slice.
// P relay is per-wave LDS (in-order LDS pipe) -> no barrier between P and PV.
__global__ __launch_bounds__(128) void attn_mfma(ushort* __restrict__ qkv) {
  __shared__ ushort lk[64 * 72];      // K chunk  [key][64+8]
  __shared__ ushort lvT[64 * 72];     // V^T      [d][64+8]
  __shared__ ushort lp[2 * 64 * 72];  // per-wave P [qrow][64+8]
  const int qp = blockIdx.x, h = blockIdx.y, b = blockIdx.z;
  const int tid = threadIdx.x;
  const int g = tid >> 6, lane = tid & 63;
  const int tr = lane & 15, tq = lane >> 4;
  const int qc = qp * 2 + g;
  const int q0 = qc << 6;
  ushort* myp = &lp[g * 64 * 72];

  bf16x8 qf[4][2];
#pragma unroll
  for (int i = 0; i < 4; ++i)
#pragma unroll
    for (int s = 0; s < 2; ++s)
      qf[i][s] = *(const bf16x8*)(qkv +
                                  (size_t)(b * 256 + q0 + i * 16 + tr) * 1536 +
                                  h * 64 + s * 32 + tq * 8);

  f32x4 o[4][4];
  float pl[4][4];
#pragma unroll
  for (int i = 0; i < 4; ++i)
#pragma unroll
    for (int j = 0; j < 4; ++j) {
      o[i][j] = (f32x4)(0.f);
      pl[i][j] = 0.f;
    }

  const int key = tid >> 1, half = tid & 1;
  const int cmax = qp * 2 + 1;
  for (int c = 0; c <= cmax; ++c) {
    __syncthreads();  // protect prior chunk's lk/lvT reads
    const ushort* gk =
        qkv + (size_t)(b * 256 + c * 64 + key) * 1536 + 512 + h * 64 + half * 32;
#pragma unroll
    for (int u = 0; u < 4; ++u)
      *(uint4*)&lk[key * 72 + half * 32 + u * 8] = *(const uint4*)(gk + u * 8);
    ushort vloc[32];
#pragma unroll
    for (int u = 0; u < 4; ++u)
      *(uint4*)&vloc[u * 8] = *(const uint4*)(gk + 512 + u * 8);
#pragma unroll
    for (int dd = 0; dd < 32; ++dd)
      lvT[(half * 32 + dd) * 72 + key] = vloc[dd];
    __syncthreads();

    if (c <= qc) {
      // S = Q . K^T
      f32x4 Sv[4][4];
#pragma unroll
      for (int i = 0; i < 4; ++i)
#pragma unroll
        for (int j = 0; j < 4; ++j) Sv[i][j] = (f32x4)(0.f);
      bf16x8 kf[4][2];
#pragma unroll
      for (int j = 0; j < 4; ++j)
#pragma unroll
        for (int s = 0; s < 2; ++s)
          kf[j][s] = *(const bf16x8*)&lk[(j * 16 + tr) * 72 + s * 32 + tq * 8];
#pragma unroll
      for (int i = 0; i < 4; ++i)
#pragma unroll
        for (int j = 0; j < 4; ++j) {
          Sv[i][j] = __builtin_amdgcn_mfma_f32_16x16x32_bf16(qf[i][0], kf[j][0],
                                                             Sv[i][j], 0, 0, 0);
          Sv[i][j] = __builtin_amdgcn_mfma_f32_16x16x32_bf16(qf[i][1], kf[j][1],
                                                             Sv[i][j], 0, 0, 0);
        }
      // exp2 (Q pre-scaled) + causal mask + partial rowsums + P -> own LDS
      const bool diag = (c == qc);
#pragma unroll
      for (int i = 0; i < 4; ++i)
#pragma unroll
        for (int j = 0; j < 4; ++j)
#pragma unroll
          for (int r = 0; r < 4; ++r) {
            float e = exp2f(Sv[i][j][r]);
            if (diag && (j * 16 + tr) > (i * 16 + tq * 4 + r)) e = 0.f;
            pl[i][r] += e;
            myp[(i * 16 + tq * 4 + r) * 72 + j * 16 + tr] =
                (ushort)(__float_as_uint(e) >> 16);  // trunc: P in [0,1]
          }
      // O += P . V  (same-wave LDS RAW: in-order DS pipe, no barrier)
#pragma unroll
      for (int s = 0; s < 2; ++s) {
        bf16x8 vf[4], af[4];
#pragma unroll
        for (int jn = 0; jn < 4; ++jn)
          vf[jn] = *(const bf16x8*)&lvT[(jn * 16 + tr) * 72 + s * 32 + tq * 8];
#pragma unroll
        for (int im = 0; im < 4; ++im)
          af[im] = *(const bf16x8*)&myp[(im * 16 + tr) * 72 + s * 32 + tq * 8];
#pragma unroll
        for (int im = 0; im < 4; ++im)
#pragma unroll
          for (int jn = 0; jn < 4; ++jn)
            o[im][jn] = __builtin_amdgcn_mfma_f32_16x16x32_bf16(af[im], vf[jn],
                                                                o[im][jn], 0, 0, 0);
      }
    }
  }

#pragma unroll
  for (int i = 0; i < 4; ++i)
#pragma unroll
    for (int r = 0; r < 4; ++r) {
      float v = pl[i][r];
      v += __shfl_xor(v, 1, 64);
      v += __shfl_xor(v, 2, 64);
      v += __shfl_xor(v, 4, 64);
      v += __shfl_xor(v, 8, 64);
      pl[i][r] = 1.f / v;
    }

#pragma unroll
  for (int i = 0; i < 4; ++i)
#pragma unroll
    for (int j = 0; j < 4; ++j)
#pragma unroll
      for (int r = 0; r < 4; ++r)
        qkv[(size_t)(b * 256 + q0 + i * 16 + tq * 4 + r) * 1536 + h * 64 +
            j * 16 + tr] = f2b(o[i][j][r] * pl[i][r]);
}

// ---- fused LN1+LN2: x = LN2(LN1(x + d1) + cavec16[b]) ---------------------
__global__ __launch_bounds__(256) void ln12_kernel(
    ushort* __restrict__ x16, const uint* __restrict__ d1,
    const uint* __restrict__ cavec, const float* __restrict__ s1,
    const float* __restrict__ b1, const float* __restrict__ s2,
    const float* __restrict__ b2p) {
  const int r = blockIdx.x, t = threadIdx.x;
  const int lane = t & 63, wv = t >> 6;
  uint* xr = (uint*)x16 + (size_t)r * 256;
  uint xu = xr[t];
  uint du = d1[(size_t)r * 768 + t];
  float v0 = blo(xu) + blo(du), v1 = bhi(xu) + bhi(du);
  __shared__ float redA[4][2], redB[4][2];
  float sm = v0 + v1, sq = v0 * v0 + v1 * v1;
#pragma unroll
  for (int o = 32; o > 0; o >>= 1) {
    sm += __shfl_xor(sm, o, 64);
    sq += __shfl_xor(sq, o, 64);
  }
  if (lane == 0) {
    redA[wv][0] = sm;
    redA[wv][1] = sq;
  }
  __syncthreads();
  sm = redA[0][0] + redA[1][0] + redA[2][0] + redA[3][0];
  sq = redA[0][1] + redA[1][1] + redA[2][1] + redA[3][1];
  float mean = sm * (1.f / 512.f);
  float var = sq * (1.f / 512.f) - mean * mean;
  float rs = rsqrtf(var + 1e-5f);
  float2 sa = ((const float2*)s1)[t];
  float2 ba = ((const float2*)b1)[t];
  uint cu = cavec[(size_t)(r >> 8) * 256 + t];
  float w0 = (v0 - mean) * rs * sa.x + ba.x + blo(cu);
  float w1 = (v1 - mean) * rs * sa.y + ba.y + bhi(cu);
  sm = w0 + w1;
  sq = w0 * w0 + w1 * w1;
#pragma unroll
  for (int o = 32; o > 0; o >>= 1) {
    sm += __shfl_xor(sm, o, 64);
    sq += __shfl_xor(sq, o, 64);
  }
  if (lane == 0) {
    redB[wv][0] = sm;
    redB[wv][1] = sq;
  }
  __syncthreads();
  sm = redB[0][0] + redB[1][0] + redB[2][0] + redB[3][0];
  sq = redB[0][1] + redB[1][1] + redB[2][1] + redB[3][1];
  mean = sm * (1.f / 512.f);
  var = sq * (1.f / 512.f) - mean * mean;
  rs = rsqrtf(var + 1e-5f);
  float2 sb = ((const float2*)s2)[t];
  float2 bb = ((const float2*)b2p)[t];
  float y0 = (w0 - mean) * rs * sb.x + bb.x;
  float y1 = (w1 - mean) * rs * sb.y + bb.y;
  xr[t] = pack2(y0, y1);
}

// -------- LayerNorm: x16 = bf16(LN(x16 + delta) * sc + bi), in place --------
__global__ __launch_bounds__(256) void ln_kernel(
    ushort* __restrict__ x16, const uint* __restrict__ delta, int DsU,
    const float* __restrict__ sc, const float* __restrict__ bi) {
  const int r = blockIdx.x, t = threadIdx.x;
  const int lane = t & 63, wv = t >> 6;
  uint* xr = (uint*)x16 + (size_t)r * 256;
  uint xu = xr[t];
  uint du = delta[(size_t)r * DsU + t];
  float v0 = blo(xu) + blo(du), v1 = bhi(xu) + bhi(du);
  float sm = v0 + v1, sq = v0 * v0 + v1 * v1;
#pragma unroll
  for (int o = 32; o > 0; o >>= 1) {
    sm += __shfl_xor(sm, o, 64);
    sq += __shfl_xor(sq, o, 64);
  }
  __shared__ float red[4][2];
  if (lane == 0) {
    red[wv][0] = sm;
    red[wv][1] = sq;
  }
  __syncthreads();
  sm = red[0][0] + red[1][0] + red[2][0] + red[3][0];
  sq = red[0][1] + red[1][1] + red[2][1] + red[3][1];
  float mean = sm * (1.f / 512.f);
  float var = sq * (1.f / 512.f) - mean * mean;
  float rs = rsqrtf(var + 1e-5f);
  float2 s2 = ((const float2*)sc)[t];
  float2 b2 = ((const float2*)bi)[t];
  float y0 = (v0 - mean) * rs * s2.x + b2.x;
  float y1 = (v1 - mean) * rs * s2.y + b2.y;
  xr[t] = pack2(y0, y1);
}

extern "C" void kernel_launch(void* const* d_in, const int* in_sizes, int n_in,
                              void* d_out, int out_size, void* d_ws,
                              size_t ws_size, hipStream_t stream) {
  (void)in_sizes; (void)n_in; (void)out_size; (void)ws_size;
  const float* z = (const float*)d_in[0];
  const int* tgt = (const int*)d_in[1];
  const float* emb = (const float*)d_in[2];
  const float* pos = (const float*)d_in[3];
  const float* projw = (const float*)d_in[4];
  const float* projb = (const float*)d_in[5];
  const float* saw = (const float*)d_in[6];
  const float* sab = (const float*)d_in[7];
  const float* saow = (const float*)d_in[8];
  const float* saob = (const float*)d_in[9];
  const float* caw = (const float*)d_in[10];
  const float* cab = (const float*)d_in[11];
  const float* caow = (const float*)d_in[12];
  const float* caob = (const float*)d_in[13];
  const float* ln1s = (const float*)d_in[14];
  const float* ln1b = (const float*)d_in[15];
  const float* ln2s = (const float*)d_in[16];
  const float* ln2b = (const float*)d_in[17];
  const float* ln3s = (const float*)d_in[18];
  const float* ln3b = (const float*)d_in[19];
  const float* ff1w = (const float*)d_in[20];
  const float* ff1b = (const float*)d_in[21];
  const float* ff2w = (const float*)d_in[22];
  const float* ff2b = (const float*)d_in[23];
  const float* fcw = (const float*)d_in[24];
  const float* fcb = (const float*)d_in[25];

  // workspace carve — TOTAL ~103 MiB:
  // [0,16M)    x16 bf16 residual
  // [16M,64M)  qkv 48M (attn in-place; out-proj delta in dead k-slice);
  //            FF phase: hbuf 32M + fdel 16M
  // [64M,66M)  bf16 smalls: z16(128x512) memv16(128x512) cav16(6x128x512)
  //            cavec16(6x128x512) — rows 64..127 are junk (M padded to 128)
  // [66M,~103M) bf16 weights (converted once per launch)
  char* w8 = (char*)d_ws;
  ushort* x16 = (ushort*)w8;
  ushort* qkv = (ushort*)(w8 + (16u << 20));
  ushort* hbuf = qkv;
  ushort* fdel = (ushort*)(w8 + (48u << 20));
  ushort* z16 = (ushort*)(w8 + (64u << 20));
  ushort* memv16 = z16 + 128 * 512;
  ushort* cav16 = memv16 + 128 * 512;
  ushort* cavec16 = cav16 + (size_t)L_ * 128 * 512;
  ushort* wsaw = (ushort*)(w8 + (66u << 20));
  ushort* wsaow = wsaw + (size_t)L_ * 1536 * 512;
  ushort* wff1 = wsaow + (size_t)L_ * 512 * 512;
  ushort* wff2 = wff1 + (size_t)L_ * 2048 * 512;
  ushort* wfcw = wff2 + (size_t)L_ * 512 * 2048;

  // one-time weight conversions (fp32 -> bf16)
  conv_kernel<<<(L_ * 1536 * 512) / 512, 256, 0, stream>>>(saw, wsaw);
  conv_kernel<<<(L_ * 512 * 512) / 512, 256, 0, stream>>>(saow, wsaow);
  conv_kernel<<<(L_ * 2048 * 512) / 512, 256, 0, stream>>>(ff1w, wff1);
  conv_kernel<<<(L_ * 512 * 2048) / 512, 256, 0, stream>>>(ff2w, wff2);
  conv_kernel<<<(V_ * 512) / 512, 256, 0, stream>>>(fcw, wfcw);
  conv_kernel<<<(B_ * 512) / 512, 256, 0, stream>>>(z, z16);

  embed_kernel<<<16384, 256, 0, stream>>>(tgt, emb, pos, x16);

  // collapsed cross-attention (kv len 1) via padded-M MFMA, all batched:
  // memv16 = z16 . projw^T + projb
  gemm_btf<<<dim3(4, 1, 1), 256, 0, stream>>>(z16, 0, projw, 0, projb, 0,
                                              memv16, 0, 512, 512, 512, 512, 512);
  // cav16[l] = memv16 . Wv_l^T + bv_l
  gemm_btf<<<dim3(4, 1, L_), 256, 0, stream>>>(
      memv16, 0, caw + 1024 * 512, (long)1536 * 512, cab + 1024, 1536, cav16,
      (long)128 * 512, 512, 512, 512, 512, 512);
  // cavec16[l] = cav16[l] . Wo_l^T + bo_l
  gemm_btf<<<dim3(4, 1, L_), 256, 0, stream>>>(
      cav16, (long)128 * 512, caow, (long)512 * 512, caob, 512, cavec16,
      (long)128 * 512, 512, 512, 512, 512, 512);

  for (int i = 0; i < L_; ++i) {
    // QKV (+ Q pre-scale): qkv = x16 . sa_w^T + sa_b
    gemm_rs<4><<<dim3(12, 128), 256, 0, stream>>>(
        x16, wsaw + (size_t)i * 1536 * 512, sab + i * 1536, qkv, 1536, 512, 512,
        512, 1536);
    attn_mfma<<<dim3(2, H_, B_), 128, 0, stream>>>(qkv);
    // out-proj -> dead k-slice
    gemm_rs<0><<<dim3(4, 128), 256, 0, stream>>>(
        qkv, wsaow + (size_t)i * 512 * 512, saob + i * 512, qkv + 512, 512, 512,
        1536, 512, 1536);
    // fused LN1 + cross-attn add + LN2
    ln12_kernel<<<16384, 256, 0, stream>>>(
        x16, (const uint*)(qkv + 512), (const uint*)(cavec16 + (size_t)i * 128 * 512),
        ln1s + i * 512, ln1b + i * 512, ln2s + i * 512, ln2b + i * 512);
    // FFN split into two DFF=1024 chunks
    gemm_rs<1><<<dim3(8, 128), 256, 0, stream>>>(
        x16, wff1 + (size_t)i * 2048 * 512, ff1b + i * 2048, hbuf, 1024, 512,
        512, 512, 1024);
    gemm_rs<0><<<dim3(4, 128), 256, 0, stream>>>(
        hbuf, wff2 + (size_t)i * 512 * 2048, ff2b + i * 512, fdel, 512, 1024,
        1024, 2048, 512);
    gemm_rs<1><<<dim3(8, 128), 256, 0, stream>>>(
        x16, wff1 + ((size_t)i * 2048 + 1024) * 512, ff1b + i * 2048 + 1024,
        hbuf, 1024, 512, 512, 512, 1024);
    gemm_rs<2><<<dim3(4, 128), 256, 0, stream>>>(
        hbuf, wff2 + (size_t)i * 512 * 2048 + 1024, (const float*)0, fdel, 512,
        1024, 1024, 2048, 512);
    ln_kernel<<<16384, 256, 0, stream>>>(x16, (const uint*)fdel, 256,
                                         ln3s + i * 512, ln3b + i * 512);
  }
  gemm_bt<3><<<dim3(1, 128), 256, 0, stream>>>(x16, wfcw, fcb, d_out, 128, 512,
                                               512, 512, 128);
}